// Round 1
// baseline (1851.559 us; speedup 1.0000x reference)
//
#include <hip/hip_runtime.h>
#include <math.h>

// Problem constants (B,T,H,K,V,BT) = (2,8192,16,32,64,64)
#define Tt 8192
#define Hh 16
#define NCH 4096        // chunk-heads, ch = c*32 + (b*16+h)
// Workspace layout (floats):
//   wsW  [NCH][2048]  w (64x32 row-major)
//   wsU  [NCH][4096]  u (64x64 row-major)
//   wsM  [NCH][1024]  M = diag(egl) - Kd^T W
//   wsC  [NCH][2048]  C = Kd^T U   -> overwritten by entering-S (32x64) in scanC
//   wsMs [256][1024]  per-segment composed M
//   wsCs [256][2048]  per-segment composed C
//   wsSs [256][2048]  entering S per segment
// total = (4096*9216 + 256*5120)*4 B = 156.3 MB

#define OFF_U   ((size_t)NCH*2048)
#define OFF_M   ((size_t)NCH*6144)
#define OFF_C   ((size_t)NCH*7168)
#define OFF_MS  ((size_t)NCH*9216)
#define OFF_CS  (OFF_MS + (size_t)256*1024)
#define OFF_SS  (OFF_CS + (size_t)256*2048)

__device__ __forceinline__ float softplusf(float x) {
  return fmaxf(x, 0.f) + log1pf(__expf(-fabsf(x)));
}

// ---------------- Phase 1: per-chunk intra quantities + (M,C) ----------------
// 512 threads/chunk: halves per-thread critical path vs the 256-thread version,
// halves Akk barrier count (4 tiles of 16 cols), and with LDS ~52KB allows
// 3 blocks * 8 waves = 24 waves/CU (launch_bounds(512,6) keeps VGPR under the cap).
__global__ __launch_bounds__(512, 6) void kda_phase1(
    const float* __restrict__ kin, const float* __restrict__ vin,
    const float* __restrict__ graw, const float* __restrict__ beta,
    const float* __restrict__ A_log, const float* __restrict__ dt_bias,
    float* __restrict__ ws)
{
  __shared__ float sG[64*33];   // gcum (s33) -> w (s32, first 2048)
  __shared__ float sK[64*33];   // kn -> kd (s33)
  __shared__ float sL[64*64];   // L col-major -> k_egb(s32) -> vb(s64) -> u(s64)
  __shared__ float sT[64*65];   // P(s33)+Qb(16x32 @2112) -> Tm (s65)
  __shared__ float sC2[2*272];  // per-group off-diag temp
  __shared__ float sEgl[32];

  const int tid = threadIdx.x;
  const int ch = blockIdx.x;
  const int c = ch >> 5, bh = ch & 31;
  const int b = bh >> 4, h = bh & 15;
  const int t0 = c*64;
  const int iq = tid >> 3, kq = (tid & 7)*4;

  float* wsW = ws;
  float* wsU = ws + OFF_U;
  float* wsM = ws + OFF_M;
  float* wsCc= ws + OFF_C;

  const float negA = -__expf(A_log[h]);

  { // gate g into sG (4 elems/thread)
    const float* gr = graw + (((size_t)b*Tt + t0 + iq)*Hh + h)*32 + kq;
    const float* db = dt_bias + h*32 + kq;
    #pragma unroll
    for (int r = 0; r < 4; ++r)
      sG[iq*33 + kq + r] = negA * softplusf(gr[r] + db[r]);
  }
  __syncthreads();
  if (tid < 32) { // cumsum over time per k, register-chunked (pipelined loads)
    float c0 = 0.f;
    for (int blk = 0; blk < 4; ++blk) {
      float v[16];
      #pragma unroll
      for (int i = 0; i < 16; ++i) v[i] = sG[(blk*16+i)*33 + tid];
      #pragma unroll
      for (int i = 0; i < 16; ++i) { c0 += v[i]; sG[(blk*16+i)*33 + tid] = c0; }
    }
  }
  { // k row-l2-normalize into sK (8 threads/row)
    const float* kp = kin + (((size_t)b*Tt + t0 + iq)*Hh + h)*32 + kq;
    float kr[4]; float ss = 0.f;
    #pragma unroll
    for (int r = 0; r < 4; ++r) { kr[r] = kp[r]; ss += kr[r]*kr[r]; }
    ss += __shfl_xor(ss, 1); ss += __shfl_xor(ss, 2); ss += __shfl_xor(ss, 4);
    const float sc = 1.f / fmaxf(sqrtf(ss), 1e-6f);
    #pragma unroll
    for (int r = 0; r < 4; ++r) sK[iq*33 + kq + r] = kr[r]*sc;
  }
  __syncthreads();

  // ---- Akk in 16-column tiles (4 tiles, 8 barriers total) ----
  const float b_cm = beta[((size_t)b*Tt + t0 + (tid & 63))*Hh + h];
  float* P  = sT;          // 64x32 s33
  float* Qb = sT + 2112;   // 16x32 s32
  const int i64 = tid & 63, jj2 = (tid >> 6)*2;
  for (int jt = 0; jt < 4; ++jt) {
    const int j0 = jt*16;
    #pragma unroll
    for (int r = 0; r < 4; ++r) {
      const int idx = iq*33 + kq + r;
      P[idx] = sK[idx] * __expf(fminf(sG[idx] - sG[j0*33 + kq + r], 0.f));
    }
    {
      const int jj = tid >> 5, kk = tid & 31;
      Qb[jj*32 + kk] = sK[(j0+jj)*33 + kk] * __expf(sG[j0*33 + kk] - sG[(j0+jj)*33 + kk]);
    }
    __syncthreads();
    float a0 = 0.f, a1 = 0.f;
    for (int k8 = 0; k8 < 4; ++k8) {   // k in chunks of 8: bounded reg pressure
      const int k0 = k8*8;
      float qa[8], qb[8];
      #pragma unroll
      for (int t4 = 0; t4 < 2; ++t4) {
        float4 xa = *(const float4*)(Qb + (jj2  )*32 + k0 + t4*4);
        float4 xb = *(const float4*)(Qb + (jj2+1)*32 + k0 + t4*4);
        qa[t4*4+0]=xa.x; qa[t4*4+1]=xa.y; qa[t4*4+2]=xa.z; qa[t4*4+3]=xa.w;
        qb[t4*4+0]=xb.x; qb[t4*4+1]=xb.y; qb[t4*4+2]=xb.z; qb[t4*4+3]=xb.w;
      }
      #pragma unroll
      for (int kk = 0; kk < 8; ++kk) {
        const float p = P[i64*33 + k0 + kk];
        a0 += p * qa[kk]; a1 += p * qb[kk];
      }
    }
    const int j_0 = j0 + jj2;
    sL[(j_0  )*64 + i64] = (i64 > j_0  ) ? a0*b_cm : 0.f;
    sL[(j_0+1)*64 + i64] = (i64 > j_0+1) ? a1*b_cm : 0.f;
    __syncthreads();
  }

  // ---- Tm = (I + L)^-1, blocked 16x16 forward substitution ----
  for (int e = tid; e < 4096; e += 512) {
    const int row = e >> 6, col = e & 63;
    sT[row*65 + col] = (row == col) ? 1.f : 0.f;
  }
  __syncthreads();
  // diagonal blocks: all cross-iteration deps are lane-local -> no barriers
  if (tid < 64) {
    const int p = tid >> 4, col = tid & 15;
    for (int i = 1; i < 16; ++i) {
      const int gi = p*16 + i, gc = p*16 + col;
      float acc = 0.f;
      for (int j = 0; j < i; ++j)
        acc -= sL[(p*16+j)*64 + gi] * sT[(p*16+j)*65 + gc];
      sT[gi*65 + gc] = acc + ((i == col) ? 1.f : 0.f);
    }
  }
  __syncthreads();
  // off-diagonal blocks: 2 groups x 256 threads (1 elem/thread), 3 rounds
  {
    const int grp = tid >> 8, gl = tid & 255;
    const int ri = gl & 15, cc = gl >> 4;
    auto offblk1 = [&](int p, int q) {
      float acc = 0.f;
      for (int m = q; m < p; ++m) {
        #pragma unroll
        for (int j = 0; j < 16; ++j)
          acc += sL[(m*16+j)*64 + p*16+ri] * sT[(m*16+j)*65 + q*16+cc];
      }
      sC2[grp*272 + ri*17 + cc] = acc;
    };
    auto offblk2 = [&](int p, int q) {
      float bacc = 0.f;
      #pragma unroll
      for (int j = 0; j < 16; ++j)
        bacc += sT[(p*16+ri)*65 + p*16 + j] * sC2[grp*272 + j*17 + cc];
      sT[(p*16+ri)*65 + q*16+cc] = -bacc;
    };
    int p = grp ? 2 : 1, q = grp ? 1 : 0;          // r1: (1,0) | (2,1)
    offblk1(p,q); __syncthreads(); offblk2(p,q); __syncthreads();
    p = grp ? 3 : 2; q = grp ? 2 : 0;              // r2: (2,0) | (3,2)
    offblk1(p,q); __syncthreads(); offblk2(p,q); __syncthreads();
    p = 3; q = grp ? 1 : 0;                        // r3: (3,0) | (3,1)
    offblk1(p,q); __syncthreads(); offblk2(p,q); __syncthreads();
  }

  { // k_egb (s32 into sL[0..2047]); kd overwrites sK (s33); egl
    const float b_row = beta[((size_t)b*Tt + t0 + iq)*Hh + h];
    #pragma unroll
    for (int r = 0; r < 4; ++r) {
      const int idx = iq*33 + kq + r;
      const float g = sG[idx], kn = sK[idx];
      sL[iq*32 + kq + r] = b_row * kn * __expf(g);
      sK[idx] = kn * __expf(sG[63*33 + kq + r] - g);
    }
    if (tid < 32) sEgl[tid] = __expf(sG[63*33 + tid]);
  }
  __syncthreads();

  { // w = Tm @ k_egb -> global + sG (s32; gcum dead)
    float acc[4] = {0.f,0.f,0.f,0.f};
    for (int j = 0; j <= iq; ++j) {
      const float t = sT[iq*65 + j];
      const float4 e0 = *(const float4*)(sL + j*32 + kq);
      acc[0]+=t*e0.x; acc[1]+=t*e0.y; acc[2]+=t*e0.z; acc[3]+=t*e0.w;
    }
    float4 o4; o4.x=acc[0]; o4.y=acc[1]; o4.z=acc[2]; o4.w=acc[3];
    *(float4*)(wsW + (size_t)ch*2048 + tid*4) = o4;
    *(float4*)(sG + tid*4) = o4;
  }
  __syncthreads();

  { // vb = beta_j * v into sL (s64)
    #pragma unroll
    for (int r = 0; r < 2; ++r) {
      const int f = tid + 512*r;
      const int j = f >> 4, qd = f & 15;
      const float bj = beta[((size_t)b*Tt + t0 + j)*Hh + h];
      float4 v4 = *(const float4*)(vin + (((size_t)b*Tt + t0 + j)*Hh + h)*64 + qd*4);
      v4.x *= bj; v4.y *= bj; v4.z *= bj; v4.w *= bj;
      *(float4*)(sL + j*64 + qd*4) = v4;
    }
  }
  __syncthreads();

  float uacc[8];
  { // u = Tm @ vb -> wsU (and regs)
    const int vs = (tid & 7)*8;
    #pragma unroll
    for (int r = 0; r < 8; ++r) uacc[r] = 0.f;
    for (int j = 0; j <= iq; ++j) {
      const float t = sT[iq*65 + j];
      const float4 e0 = *(const float4*)(sL + j*64 + vs);
      const float4 e1 = *(const float4*)(sL + j*64 + vs + 4);
      uacc[0]+=t*e0.x; uacc[1]+=t*e0.y; uacc[2]+=t*e0.z; uacc[3]+=t*e0.w;
      uacc[4]+=t*e1.x; uacc[5]+=t*e1.y; uacc[6]+=t*e1.z; uacc[7]+=t*e1.w;
    }
    #pragma unroll
    for (int rr = 0; rr < 2; ++rr) {
      float4 o4; o4.x=uacc[rr*4]; o4.y=uacc[rr*4+1]; o4.z=uacc[rr*4+2]; o4.w=uacc[rr*4+3];
      *(float4*)(wsU + (size_t)ch*4096 + tid*8 + rr*4) = o4;
    }
  }
  __syncthreads();       // all vb reads done
  { // u into sL (s64)
    const int vs = (tid & 7)*8;
    #pragma unroll
    for (int rr = 0; rr < 2; ++rr) {
      float4 o4; o4.x=uacc[rr*4]; o4.y=uacc[rr*4+1]; o4.z=uacc[rr*4+2]; o4.w=uacc[rr*4+3];
      *(float4*)(sL + iq*64 + vs + rr*4) = o4;
    }
  }
  __syncthreads();

  { // M = diag(egl) - Kd^T W ; C = Kd^T U  (16 threads per output row a)
    const int a = tid >> 4, b2 = (tid & 15)*2, v4 = (tid & 15)*4;
    float mA[2] = {0.f, 0.f};
    float cA[4] = {0.f, 0.f, 0.f, 0.f};
    for (int t = 0; t < 64; ++t) {
      const float kd = sK[t*33 + a];
      const float2 wv = *(const float2*)(sG + t*32 + b2);
      mA[0]+=kd*wv.x; mA[1]+=kd*wv.y;
      const float4 u0 = *(const float4*)(sL + t*64 + v4);
      cA[0]+=kd*u0.x; cA[1]+=kd*u0.y; cA[2]+=kd*u0.z; cA[3]+=kd*u0.w;
    }
    float2 m2;
    m2.x = ((a == b2  ) ? sEgl[a] : 0.f) - mA[0];
    m2.y = ((a == b2+1) ? sEgl[a] : 0.f) - mA[1];
    *(float2*)(wsM + (size_t)ch*1024 + tid*2) = m2;
    float4 c4; c4.x=cA[0]; c4.y=cA[1]; c4.z=cA[2]; c4.w=cA[3];
    *(float4*)(wsCc + (size_t)ch*2048 + tid*4) = c4;
  }
}

// ---------------- scanA: compose 16 chunk maps per segment (V-split x4) ----------------
// 1-deep HBM prefetch; 2 barriers/iteration.
__global__ __launch_bounds__(256) void kda_scanA(float* __restrict__ ws)
{
  __shared__ float sMa[32*33];
  __shared__ float sMc[32*33];
  __shared__ float sCa[32*18];
  const int tid = threadIdx.x;
  const int vt = blockIdx.x & 3, seg = (blockIdx.x >> 2) & 7, bh = blockIdx.x >> 5;
  const int v0 = vt*16;
  const int a = tid >> 3, b4 = (tid & 7)*4, c2 = (tid & 7)*2;
  const float* wsM = ws + OFF_M;
  const float* wsC = ws + OFF_C;

  #pragma unroll
  for (int r = 0; r < 4; ++r) sMa[a*33 + b4 + r] = (a == b4 + r) ? 1.f : 0.f;
  sCa[a*18 + c2] = 0.f; sCa[a*18 + c2 + 1] = 0.f;

  int ch = (seg*16)*32 + bh;
  float4 m4 = *(const float4*)(wsM + (size_t)ch*1024 + tid*4);
  float2 cc = *(const float2*)(wsC + (size_t)ch*2048 + a*64 + v0 + c2);

  for (int i = 0; i < 16; ++i) {
    sMc[a*33+b4+0]=m4.x; sMc[a*33+b4+1]=m4.y; sMc[a*33+b4+2]=m4.z; sMc[a*33+b4+3]=m4.w;
    __syncthreads();
    float4 m4n = m4; float2 ccn = cc;
    if (i < 15) {   // prefetch next chunk while computing this one
      const int chn = (seg*16 + i + 1)*32 + bh;
      m4n = *(const float4*)(wsM + (size_t)chn*1024 + tid*4);
      ccn = *(const float2*)(wsC + (size_t)chn*2048 + a*64 + v0 + c2);
    }
    float cn0 = cc.x, cn1 = cc.y;
    float mn0=0.f, mn1=0.f, mn2=0.f, mn3=0.f;
    for (int bb = 0; bb < 32; ++bb) {
      const float m = sMc[a*33 + bb];
      const float2 s2 = *(const float2*)(sCa + bb*18 + c2);
      cn0 += m*s2.x; cn1 += m*s2.y;
      mn0 += m*sMa[bb*33+b4+0]; mn1 += m*sMa[bb*33+b4+1];
      mn2 += m*sMa[bb*33+b4+2]; mn3 += m*sMa[bb*33+b4+3];
    }
    __syncthreads();
    sCa[a*18+c2] = cn0; sCa[a*18+c2+1] = cn1;
    sMa[a*33+b4+0]=mn0; sMa[a*33+b4+1]=mn1; sMa[a*33+b4+2]=mn2; sMa[a*33+b4+3]=mn3;
    m4 = m4n; cc = ccn;
  }
  // epilogue reads only own-written elements: no barrier needed
  const size_t sid = (size_t)(bh*8 + seg);
  float* wsMs = ws + OFF_MS;
  float* wsCs = ws + OFF_CS;
  if (vt == 0) {
    #pragma unroll
    for (int r = 0; r < 4; ++r) wsMs[sid*1024 + tid*4 + r] = sMa[a*33+b4+r];
  }
  float2 co; co.x = sCa[a*18+c2]; co.y = sCa[a*18+c2+1];
  *(float2*)(wsCs + sid*2048 + a*64 + v0 + c2) = co;
}

// ---------------- scanB: scan 8 segments per bh (V-split x4, grid 128) ----------------
__global__ __launch_bounds__(256) void kda_scanB(float* __restrict__ ws)
{
  __shared__ float sS[32*18];
  __shared__ float sM[32*33];
  const int tid = threadIdx.x;
  const int vt = blockIdx.x & 3, bh = blockIdx.x >> 2;
  const int v0 = vt*16;
  const int a = tid >> 3, b4 = (tid & 7)*4, c2 = (tid & 7)*2;
  const float* wsMs = ws + OFF_MS;
  const float* wsCs = ws + OFF_CS;
  float* wsSs = ws + OFF_SS;

  float s0 = 0.f, s1 = 0.f;
  sS[a*18 + c2] = 0.f; sS[a*18 + c2 + 1] = 0.f;
  const size_t sid0 = (size_t)(bh*8);
  float4 m4 = *(const float4*)(wsMs + sid0*1024 + tid*4);
  float2 cc = *(const float2*)(wsCs + sid0*2048 + a*64 + v0 + c2);

  for (int seg = 0; seg < 8; ++seg) {
    const size_t sid = (size_t)(bh*8 + seg);
    *(float2*)(wsSs + sid*2048 + a*64 + v0 + c2) = make_float2(s0, s1);
    sM[a*33+b4+0]=m4.x; sM[a*33+b4+1]=m4.y; sM[a*33+b4+2]=m4.z; sM[a*33+b4+3]=m4.w;
    __syncthreads();
    float4 m4n = m4; float2 ccn = cc;
    if (seg < 7) {
      m4n = *(const float4*)(wsMs + (sid+1)*1024 + tid*4);
      ccn = *(const float2*)(wsCs + (sid+1)*2048 + a*64 + v0 + c2);
    }
    float n0 = cc.x, n1 = cc.y;
    for (int bb = 0; bb < 32; ++bb) {
      const float m = sM[a*33 + bb];
      const float2 s2 = *(const float2*)(sS + bb*18 + c2);
      n0 += m*s2.x; n1 += m*s2.y;
    }
    __syncthreads();
    s0 = n0; s1 = n1;
    sS[a*18+c2] = s0; sS[a*18+c2+1] = s1;
    m4 = m4n; cc = ccn;
  }
}

// ---------------- scanC: replay chunks, write entering-S over C slot (V-split x4) ----------------
__global__ __launch_bounds__(256) void kda_scanC(float* __restrict__ ws)
{
  __shared__ float sM[32*33];
  __shared__ float sS[32*18];
  const int tid = threadIdx.x;
  const int vt = blockIdx.x & 3, seg = (blockIdx.x >> 2) & 7, bh = blockIdx.x >> 5;
  const int v0 = vt*16;
  const int a = tid >> 3, b4 = (tid & 7)*4, c2 = (tid & 7)*2;
  const float* wsM = ws + OFF_M;
  float* wsC = ws + OFF_C;
  const float* wsSs = ws + OFF_SS;

  const size_t sid = (size_t)(bh*8 + seg);
  float s0, s1;
  {
    float2 sv = *(const float2*)(wsSs + sid*2048 + a*64 + v0 + c2);
    s0 = sv.x; s1 = sv.y;
    sS[a*18 + c2] = s0; sS[a*18 + c2 + 1] = s1;
  }
  int ch = (seg*16)*32 + bh;
  float4 m4 = *(const float4*)(wsM + (size_t)ch*1024 + tid*4);
  float2 cc = *(const float2*)(wsC + (size_t)ch*2048 + a*64 + v0 + c2);

  for (int i = 0; i < 16; ++i) {
    const int chc = (seg*16 + i)*32 + bh;
    sM[a*33+b4+0]=m4.x; sM[a*33+b4+1]=m4.y; sM[a*33+b4+2]=m4.z; sM[a*33+b4+3]=m4.w;
    // entering-S over the consumed C slice (own elements; cc already in regs)
    *(float2*)(wsC + (size_t)chc*2048 + a*64 + v0 + c2) = make_float2(s0, s1);
    __syncthreads();
    float4 m4n = m4; float2 ccn = cc;
    if (i < 15) {   // prefetch next chunk's (M,C); same-thread same-address order vs next overwrite
      const int chn = (seg*16 + i + 1)*32 + bh;
      m4n = *(const float4*)(wsM + (size_t)chn*1024 + tid*4);
      ccn = *(const float2*)(wsC + (size_t)chn*2048 + a*64 + v0 + c2);
    }
    float n0 = cc.x, n1 = cc.y;
    for (int bb = 0; bb < 32; ++bb) {
      const float m = sM[a*33 + bb];
      const float2 s2 = *(const float2*)(sS + bb*18 + c2);
      n0 += m*s2.x; n1 += m*s2.y;
    }
    __syncthreads();
    s0 = n0; s1 = n1;
    sS[a*18+c2] = s0; sS[a*18+c2+1] = s1;
    m4 = m4n; cc = ccn;
  }
}

// ---------------- Phase 3: Aqk + output (o = Aqk@u + (qg - Aqk@w)@S) ----------------
__global__ __launch_bounds__(512, 6) void kda_phase3(
    const float* __restrict__ qin, const float* __restrict__ kin,
    const float* __restrict__ graw,
    const float* __restrict__ A_log, const float* __restrict__ dt_bias,
    const float* __restrict__ ws, float* __restrict__ out)
{
  __shared__ float sG[64*33];   // gcum (s33) -> S (s64, first 2048)
  __shared__ float sQ[64*33];   // qn -> qeff
  __shared__ float sA[64*65];   // Aqk
  __shared__ float sV[64*64];   // P/Qb scratch -> w (s32) -> u (s64)

  const int tid = threadIdx.x;
  const int ch = blockIdx.x;
  const int c = ch >> 5, bh = ch & 31;
  const int b = bh >> 4, h = bh & 15;
  const int t0 = c*64;
  const int iq = tid >> 3, kq = (tid & 7)*4;

  const float* wsW = ws;            // w (64x32)
  const float* wsU = ws + OFF_U;    // u (64x64)
  const float* wsS = ws + OFF_C;    // entering S (32x64) written by scanC

  const float negA = -__expf(A_log[h]);
  {
    const float* gr = graw + (((size_t)b*Tt + t0 + iq)*Hh + h)*32 + kq;
    const float* db = dt_bias + h*32 + kq;
    #pragma unroll
    for (int r = 0; r < 4; ++r)
      sG[iq*33 + kq + r] = negA * softplusf(gr[r] + db[r]);
  }
  __syncthreads();
  if (tid < 32) { // register-chunked cumsum
    float c0 = 0.f;
    for (int blk = 0; blk < 4; ++blk) {
      float v[16];
      #pragma unroll
      for (int i = 0; i < 16; ++i) v[i] = sG[(blk*16+i)*33 + tid];
      #pragma unroll
      for (int i = 0; i < 16; ++i) { c0 += v[i]; sG[(blk*16+i)*33 + tid] = c0; }
    }
  }
  float knr[4];
  { // q (l2norm * K^-1/2) into sQ; k (l2norm) in registers
    const float* qp = qin + (((size_t)b*Tt + t0 + iq)*Hh + h)*32 + kq;
    float qr[4]; float ssq = 0.f;
    #pragma unroll
    for (int r = 0; r < 4; ++r) { qr[r] = qp[r]; ssq += qr[r]*qr[r]; }
    ssq += __shfl_xor(ssq, 1); ssq += __shfl_xor(ssq, 2); ssq += __shfl_xor(ssq, 4);
    const float scq = 0.17677669529663687f / fmaxf(sqrtf(ssq), 1e-6f);
    #pragma unroll
    for (int r = 0; r < 4; ++r) sQ[iq*33 + kq + r] = qr[r]*scq;

    const float* kp = kin + (((size_t)b*Tt + t0 + iq)*Hh + h)*32 + kq;
    float ssk = 0.f;
    #pragma unroll
    for (int r = 0; r < 4; ++r) { knr[r] = kp[r]; ssk += knr[r]*knr[r]; }
    ssk += __shfl_xor(ssk, 1); ssk += __shfl_xor(ssk, 2); ssk += __shfl_xor(ssk, 4);
    const float sck = 1.f / fmaxf(sqrtf(ssk), 1e-6f);
    #pragma unroll
    for (int r = 0; r < 4; ++r) knr[r] *= sck;
  }
  __syncthreads();

  float* P  = sV;          // s33
  float* Qb = sV + 2112;   // 16x32 s32
  const int i64 = tid & 63, jj2 = (tid >> 6)*2;
  for (int jt = 0; jt < 4; ++jt) {
    const int j0 = jt*16;
    #pragma unroll
    for (int r = 0; r < 4; ++r) {
      const int idx = iq*33 + kq + r;
      P[idx] = sQ[idx] * __expf(fminf(sG[idx] - sG[j0*33 + kq + r], 0.f));
    }
    if (iq >= j0 && iq < j0 + 16) {
      const int jj = iq - j0;
      #pragma unroll
      for (int r = 0; r < 4; ++r)
        Qb[jj*32 + kq + r] = knr[r] * __expf(sG[j0*33 + kq + r] - sG[iq*33 + kq + r]);
    }
    __syncthreads();
    float a0 = 0.f, a1 = 0.f;
    for (int k8 = 0; k8 < 4; ++k8) {
      const int k0 = k8*8;
      float qa[8], qb[8];
      #pragma unroll
      for (int t4 = 0; t4 < 2; ++t4) {
        float4 xa = *(const float4*)(Qb + (jj2  )*32 + k0 + t4*4);
        float4 xb = *(const float4*)(Qb + (jj2+1)*32 + k0 + t4*4);
        qa[t4*4+0]=xa.x; qa[t4*4+1]=xa.y; qa[t4*4+2]=xa.z; qa[t4*4+3]=xa.w;
        qb[t4*4+0]=xb.x; qb[t4*4+1]=xb.y; qb[t4*4+2]=xb.z; qb[t4*4+3]=xb.w;
      }
      #pragma unroll
      for (int kk = 0; kk < 8; ++kk) {
        const float p = P[i64*33 + k0 + kk];
        a0 += p * qa[kk]; a1 += p * qb[kk];
      }
    }
    const int j_0 = j0 + jj2;
    sA[i64*65 + j_0  ] = (i64 >= j_0  ) ? a0 : 0.f;   // incl. diagonal
    sA[i64*65 + j_0+1] = (i64 >= j_0+1) ? a1 : 0.f;
    __syncthreads();
  }

  float qgr[4];
  { // qg = qn * exp(gcum) in registers (own row slice)
    #pragma unroll
    for (int r = 0; r < 4; ++r) {
      const int idx = iq*33 + kq + r;
      qgr[r] = sQ[idx] * __expf(sG[idx]);
    }
  }
  __syncthreads();   // gcum + sV scratch dead
  { // stage S into sG (s64 flat) and w into sV (s32 flat)
    *(float4*)(sG + tid*4) = *(const float4*)(wsS + (size_t)ch*2048 + tid*4);
    *(float4*)(sV + tid*4) = *(const float4*)(wsW + (size_t)ch*2048 + tid*4);
  }
  __syncthreads();
  { // qeff = qg - Aqk @ w  -> sQ
    float qe[4];
    #pragma unroll
    for (int r = 0; r < 4; ++r) qe[r] = qgr[r];
    for (int j = 0; j <= iq; ++j) {
      const float av = sA[iq*65 + j];
      const float4 w0 = *(const float4*)(sV + j*32 + kq);
      qe[0]-=av*w0.x; qe[1]-=av*w0.y; qe[2]-=av*w0.z; qe[3]-=av*w0.w;
    }
    #pragma unroll
    for (int r = 0; r < 4; ++r) sQ[iq*33 + kq + r] = qe[r];
  }
  __syncthreads();   // qeff visible; sV-w reads done
  { // stage u into sV (s64)
    #pragma unroll
    for (int rr = 0; rr < 2; ++rr) {
      const int f = tid + 512*rr;
      *(float4*)(sV + f*4) = *(const float4*)(wsU + (size_t)ch*4096 + f*4);
    }
  }
  __syncthreads();
  { // o = qeff @ S + Aqk @ u
    const int vs = (tid & 7)*8;
    float acc[8];
    #pragma unroll
    for (int r = 0; r < 8; ++r) acc[r] = 0.f;
    for (int kk = 0; kk < 32; ++kk) {
      const float qv = sQ[iq*33 + kk];
      const float4 s0 = *(const float4*)(sG + kk*64 + vs);
      const float4 s1 = *(const float4*)(sG + kk*64 + vs + 4);
      acc[0]+=qv*s0.x; acc[1]+=qv*s0.y; acc[2]+=qv*s0.z; acc[3]+=qv*s0.w;
      acc[4]+=qv*s1.x; acc[5]+=qv*s1.y; acc[6]+=qv*s1.z; acc[7]+=qv*s1.w;
    }
    for (int j = 0; j <= iq; ++j) {
      const float av = sA[iq*65 + j];
      const float4 u0 = *(const float4*)(sV + j*64 + vs);
      const float4 u1 = *(const float4*)(sV + j*64 + vs + 4);
      acc[0]+=av*u0.x; acc[1]+=av*u0.y; acc[2]+=av*u0.z; acc[3]+=av*u0.w;
      acc[4]+=av*u1.x; acc[5]+=av*u1.y; acc[6]+=av*u1.z; acc[7]+=av*u1.w;
    }
    float* op = out + (((size_t)b*Tt + t0 + iq)*Hh + h)*64 + vs;
    *(float4*)(op)     = make_float4(acc[0],acc[1],acc[2],acc[3]);
    *(float4*)(op + 4) = make_float4(acc[4],acc[5],acc[6],acc[7]);
  }
}

extern "C" void kernel_launch(void* const* d_in, const int* in_sizes, int n_in,
                              void* d_out, int out_size, void* d_ws, size_t ws_size,
                              hipStream_t stream) {
  const float* q    = (const float*)d_in[0];
  const float* k    = (const float*)d_in[1];
  const float* v    = (const float*)d_in[2];
  const float* graw = (const float*)d_in[3];
  const float* beta = (const float*)d_in[4];
  const float* A_log= (const float*)d_in[5];
  const float* dtb  = (const float*)d_in[6];
  float* out = (float*)d_out;
  float* ws  = (float*)d_ws;
  // requires ws_size >= 156.3 MB

  kda_phase1<<<NCH, 512, 0, stream>>>(k, v, graw, beta, A_log, dtb, ws);
  kda_scanA<<<1024, 256, 0, stream>>>(ws);
  kda_scanB<<<128, 256, 0, stream>>>(ws);
  kda_scanC<<<1024, 256, 0, stream>>>(ws);
  kda_phase3<<<NCH, 512, 0, stream>>>(q, k, graw, A_log, dtb, ws, out);
}

// Round 2
// 1803.966 us; speedup vs baseline: 1.0264x; 1.0264x over previous
//
#include <hip/hip_runtime.h>
#include <math.h>

// Problem constants (B,T,H,K,V,BT) = (2,8192,16,32,64,64)
#define Tt 8192
#define Hh 16
#define NCH 4096        // chunk-heads, ch = c*32 + (b*16+h)
// Workspace layout (floats):
//   wsW  [NCH][2048]  w (64x32 row-major)
//   wsU  [NCH][4096]  u (64x64 row-major)
//   wsM  [NCH][1024]  M = diag(egl) - Kd^T W
//   wsC  [NCH][2048]  C = Kd^T U   -> overwritten by entering-S (32x64) in scanC
//   wsMs [256][1024]  per-segment composed M
//   wsCs [256][2048]  per-segment composed C
//   wsSs [256][2048]  entering S per segment
// total = (4096*9216 + 256*5120)*4 B = 156.3 MB

#define OFF_U   ((size_t)NCH*2048)
#define OFF_M   ((size_t)NCH*6144)
#define OFF_C   ((size_t)NCH*7168)
#define OFF_MS  ((size_t)NCH*9216)
#define OFF_CS  (OFF_MS + (size_t)256*1024)
#define OFF_SS  (OFF_CS + (size_t)256*2048)

__device__ __forceinline__ float softplusf(float x) {
  return fmaxf(x, 0.f) + log1pf(__expf(-fabsf(x)));
}

// ---------------- Phase 1: per-chunk intra quantities + (M,C) ----------------
// 512 threads/chunk. LDS 52KB/block -> 3 blocks/CU = 24 waves/CU (LDS-bound).
// launch_bounds min-waves=4 (VGPR cap 128): R1 showed min-waves=6 forces VGPR=40
// and ~5.8GB of scratch spill traffic per dispatch. Kernel needs ~60 VGPR naturally.
__global__ __launch_bounds__(512, 4) void kda_phase1(
    const float* __restrict__ kin, const float* __restrict__ vin,
    const float* __restrict__ graw, const float* __restrict__ beta,
    const float* __restrict__ A_log, const float* __restrict__ dt_bias,
    float* __restrict__ ws)
{
  __shared__ float sG[64*33];   // gcum (s33) -> w (s32, first 2048)
  __shared__ float sK[64*33];   // kn -> kd (s33)
  __shared__ float sL[64*64];   // L col-major -> k_egb(s32) -> vb(s64) -> u(s64)
  __shared__ float sT[64*65];   // P(s33)+Qb(16x32 @2112) -> Tm (s65)
  __shared__ float sC2[2*272];  // per-group off-diag temp
  __shared__ float sEgl[32];

  const int tid = threadIdx.x;
  const int ch = blockIdx.x;
  const int c = ch >> 5, bh = ch & 31;
  const int b = bh >> 4, h = bh & 15;
  const int t0 = c*64;
  const int iq = tid >> 3, kq = (tid & 7)*4;

  float* wsW = ws;
  float* wsU = ws + OFF_U;
  float* wsM = ws + OFF_M;
  float* wsCc= ws + OFF_C;

  const float negA = -__expf(A_log[h]);

  { // gate g into sG (4 elems/thread)
    const float* gr = graw + (((size_t)b*Tt + t0 + iq)*Hh + h)*32 + kq;
    const float* db = dt_bias + h*32 + kq;
    #pragma unroll
    for (int r = 0; r < 4; ++r)
      sG[iq*33 + kq + r] = negA * softplusf(gr[r] + db[r]);
  }
  __syncthreads();
  if (tid < 32) { // cumsum over time per k, register-chunked (pipelined loads)
    float c0 = 0.f;
    for (int blk = 0; blk < 4; ++blk) {
      float v[16];
      #pragma unroll
      for (int i = 0; i < 16; ++i) v[i] = sG[(blk*16+i)*33 + tid];
      #pragma unroll
      for (int i = 0; i < 16; ++i) { c0 += v[i]; sG[(blk*16+i)*33 + tid] = c0; }
    }
  }
  { // k row-l2-normalize into sK (8 threads/row)
    const float* kp = kin + (((size_t)b*Tt + t0 + iq)*Hh + h)*32 + kq;
    float kr[4]; float ss = 0.f;
    #pragma unroll
    for (int r = 0; r < 4; ++r) { kr[r] = kp[r]; ss += kr[r]*kr[r]; }
    ss += __shfl_xor(ss, 1); ss += __shfl_xor(ss, 2); ss += __shfl_xor(ss, 4);
    const float sc = 1.f / fmaxf(sqrtf(ss), 1e-6f);
    #pragma unroll
    for (int r = 0; r < 4; ++r) sK[iq*33 + kq + r] = kr[r]*sc;
  }
  __syncthreads();

  // ---- Akk in 16-column tiles (4 tiles, 8 barriers total) ----
  const float b_cm = beta[((size_t)b*Tt + t0 + (tid & 63))*Hh + h];
  float* P  = sT;          // 64x32 s33
  float* Qb = sT + 2112;   // 16x32 s32
  const int i64 = tid & 63, jj2 = (tid >> 6)*2;
  for (int jt = 0; jt < 4; ++jt) {
    const int j0 = jt*16;
    #pragma unroll
    for (int r = 0; r < 4; ++r) {
      const int idx = iq*33 + kq + r;
      P[idx] = sK[idx] * __expf(fminf(sG[idx] - sG[j0*33 + kq + r], 0.f));
    }
    {
      const int jj = tid >> 5, kk = tid & 31;
      Qb[jj*32 + kk] = sK[(j0+jj)*33 + kk] * __expf(sG[j0*33 + kk] - sG[(j0+jj)*33 + kk]);
    }
    __syncthreads();
    float a0 = 0.f, a1 = 0.f;
    for (int k8 = 0; k8 < 4; ++k8) {   // k in chunks of 8: bounded reg pressure
      const int k0 = k8*8;
      float qa[8], qb[8];
      #pragma unroll
      for (int t4 = 0; t4 < 2; ++t4) {
        float4 xa = *(const float4*)(Qb + (jj2  )*32 + k0 + t4*4);
        float4 xb = *(const float4*)(Qb + (jj2+1)*32 + k0 + t4*4);
        qa[t4*4+0]=xa.x; qa[t4*4+1]=xa.y; qa[t4*4+2]=xa.z; qa[t4*4+3]=xa.w;
        qb[t4*4+0]=xb.x; qb[t4*4+1]=xb.y; qb[t4*4+2]=xb.z; qb[t4*4+3]=xb.w;
      }
      #pragma unroll
      for (int kk = 0; kk < 8; ++kk) {
        const float p = P[i64*33 + k0 + kk];
        a0 += p * qa[kk]; a1 += p * qb[kk];
      }
    }
    const int j_0 = j0 + jj2;
    sL[(j_0  )*64 + i64] = (i64 > j_0  ) ? a0*b_cm : 0.f;
    sL[(j_0+1)*64 + i64] = (i64 > j_0+1) ? a1*b_cm : 0.f;
    __syncthreads();
  }

  // ---- Tm = (I + L)^-1, blocked 16x16 forward substitution ----
  for (int e = tid; e < 4096; e += 512) {
    const int row = e >> 6, col = e & 63;
    sT[row*65 + col] = (row == col) ? 1.f : 0.f;
  }
  __syncthreads();
  // diagonal blocks: all cross-iteration deps are lane-local -> no barriers
  if (tid < 64) {
    const int p = tid >> 4, col = tid & 15;
    for (int i = 1; i < 16; ++i) {
      const int gi = p*16 + i, gc = p*16 + col;
      float acc = 0.f;
      for (int j = 0; j < i; ++j)
        acc -= sL[(p*16+j)*64 + gi] * sT[(p*16+j)*65 + gc];
      sT[gi*65 + gc] = acc + ((i == col) ? 1.f : 0.f);
    }
  }
  __syncthreads();
  // off-diagonal blocks: 2 groups x 256 threads (1 elem/thread), 3 rounds
  {
    const int grp = tid >> 8, gl = tid & 255;
    const int ri = gl & 15, cc = gl >> 4;
    auto offblk1 = [&](int p, int q) {
      float acc = 0.f;
      for (int m = q; m < p; ++m) {
        #pragma unroll
        for (int j = 0; j < 16; ++j)
          acc += sL[(m*16+j)*64 + p*16+ri] * sT[(m*16+j)*65 + q*16+cc];
      }
      sC2[grp*272 + ri*17 + cc] = acc;
    };
    auto offblk2 = [&](int p, int q) {
      float bacc = 0.f;
      #pragma unroll
      for (int j = 0; j < 16; ++j)
        bacc += sT[(p*16+ri)*65 + p*16 + j] * sC2[grp*272 + j*17 + cc];
      sT[(p*16+ri)*65 + q*16+cc] = -bacc;
    };
    int p = grp ? 2 : 1, q = grp ? 1 : 0;          // r1: (1,0) | (2,1)
    offblk1(p,q); __syncthreads(); offblk2(p,q); __syncthreads();
    p = grp ? 3 : 2; q = grp ? 2 : 0;              // r2: (2,0) | (3,2)
    offblk1(p,q); __syncthreads(); offblk2(p,q); __syncthreads();
    p = 3; q = grp ? 1 : 0;                        // r3: (3,0) | (3,1)
    offblk1(p,q); __syncthreads(); offblk2(p,q); __syncthreads();
  }

  { // k_egb (s32 into sL[0..2047]); kd overwrites sK (s33); egl
    const float b_row = beta[((size_t)b*Tt + t0 + iq)*Hh + h];
    #pragma unroll
    for (int r = 0; r < 4; ++r) {
      const int idx = iq*33 + kq + r;
      const float g = sG[idx], kn = sK[idx];
      sL[iq*32 + kq + r] = b_row * kn * __expf(g);
      sK[idx] = kn * __expf(sG[63*33 + kq + r] - g);
    }
    if (tid < 32) sEgl[tid] = __expf(sG[63*33 + tid]);
  }
  __syncthreads();

  { // w = Tm @ k_egb -> global + sG (s32; gcum dead)
    float acc[4] = {0.f,0.f,0.f,0.f};
    for (int j = 0; j <= iq; ++j) {
      const float t = sT[iq*65 + j];
      const float4 e0 = *(const float4*)(sL + j*32 + kq);
      acc[0]+=t*e0.x; acc[1]+=t*e0.y; acc[2]+=t*e0.z; acc[3]+=t*e0.w;
    }
    float4 o4; o4.x=acc[0]; o4.y=acc[1]; o4.z=acc[2]; o4.w=acc[3];
    *(float4*)(wsW + (size_t)ch*2048 + tid*4) = o4;
    *(float4*)(sG + tid*4) = o4;
  }
  __syncthreads();

  { // vb = beta_j * v into sL (s64)
    #pragma unroll
    for (int r = 0; r < 2; ++r) {
      const int f = tid + 512*r;
      const int j = f >> 4, qd = f & 15;
      const float bj = beta[((size_t)b*Tt + t0 + j)*Hh + h];
      float4 v4 = *(const float4*)(vin + (((size_t)b*Tt + t0 + j)*Hh + h)*64 + qd*4);
      v4.x *= bj; v4.y *= bj; v4.z *= bj; v4.w *= bj;
      *(float4*)(sL + j*64 + qd*4) = v4;
    }
  }
  __syncthreads();

  float uacc[8];
  { // u = Tm @ vb -> wsU (and regs)
    const int vs = (tid & 7)*8;
    #pragma unroll
    for (int r = 0; r < 8; ++r) uacc[r] = 0.f;
    for (int j = 0; j <= iq; ++j) {
      const float t = sT[iq*65 + j];
      const float4 e0 = *(const float4*)(sL + j*64 + vs);
      const float4 e1 = *(const float4*)(sL + j*64 + vs + 4);
      uacc[0]+=t*e0.x; uacc[1]+=t*e0.y; uacc[2]+=t*e0.z; uacc[3]+=t*e0.w;
      uacc[4]+=t*e1.x; uacc[5]+=t*e1.y; uacc[6]+=t*e1.z; uacc[7]+=t*e1.w;
    }
    #pragma unroll
    for (int rr = 0; rr < 2; ++rr) {
      float4 o4; o4.x=uacc[rr*4]; o4.y=uacc[rr*4+1]; o4.z=uacc[rr*4+2]; o4.w=uacc[rr*4+3];
      *(float4*)(wsU + (size_t)ch*4096 + tid*8 + rr*4) = o4;
    }
  }
  __syncthreads();       // all vb reads done
  { // u into sL (s64)
    const int vs = (tid & 7)*8;
    #pragma unroll
    for (int rr = 0; rr < 2; ++rr) {
      float4 o4; o4.x=uacc[rr*4]; o4.y=uacc[rr*4+1]; o4.z=uacc[rr*4+2]; o4.w=uacc[rr*4+3];
      *(float4*)(sL + iq*64 + vs + rr*4) = o4;
    }
  }
  __syncthreads();

  { // M = diag(egl) - Kd^T W ; C = Kd^T U  (16 threads per output row a)
    const int a = tid >> 4, b2 = (tid & 15)*2, v4 = (tid & 15)*4;
    float mA[2] = {0.f, 0.f};
    float cA[4] = {0.f, 0.f, 0.f, 0.f};
    for (int t = 0; t < 64; ++t) {
      const float kd = sK[t*33 + a];
      const float2 wv = *(const float2*)(sG + t*32 + b2);
      mA[0]+=kd*wv.x; mA[1]+=kd*wv.y;
      const float4 u0 = *(const float4*)(sL + t*64 + v4);
      cA[0]+=kd*u0.x; cA[1]+=kd*u0.y; cA[2]+=kd*u0.z; cA[3]+=kd*u0.w;
    }
    float2 m2;
    m2.x = ((a == b2  ) ? sEgl[a] : 0.f) - mA[0];
    m2.y = ((a == b2+1) ? sEgl[a] : 0.f) - mA[1];
    *(float2*)(wsM + (size_t)ch*1024 + tid*2) = m2;
    float4 c4; c4.x=cA[0]; c4.y=cA[1]; c4.z=cA[2]; c4.w=cA[3];
    *(float4*)(wsCc + (size_t)ch*2048 + tid*4) = c4;
  }
}

// ---------------- scanA: compose 16 chunk maps per segment (V-split x4) ----------------
// 1-deep HBM prefetch; 2 barriers/iteration.
__global__ __launch_bounds__(256) void kda_scanA(float* __restrict__ ws)
{
  __shared__ float sMa[32*33];
  __shared__ float sMc[32*33];
  __shared__ float sCa[32*18];
  const int tid = threadIdx.x;
  const int vt = blockIdx.x & 3, seg = (blockIdx.x >> 2) & 7, bh = blockIdx.x >> 5;
  const int v0 = vt*16;
  const int a = tid >> 3, b4 = (tid & 7)*4, c2 = (tid & 7)*2;
  const float* wsM = ws + OFF_M;
  const float* wsC = ws + OFF_C;

  #pragma unroll
  for (int r = 0; r < 4; ++r) sMa[a*33 + b4 + r] = (a == b4 + r) ? 1.f : 0.f;
  sCa[a*18 + c2] = 0.f; sCa[a*18 + c2 + 1] = 0.f;

  int ch = (seg*16)*32 + bh;
  float4 m4 = *(const float4*)(wsM + (size_t)ch*1024 + tid*4);
  float2 cc = *(const float2*)(wsC + (size_t)ch*2048 + a*64 + v0 + c2);

  for (int i = 0; i < 16; ++i) {
    sMc[a*33+b4+0]=m4.x; sMc[a*33+b4+1]=m4.y; sMc[a*33+b4+2]=m4.z; sMc[a*33+b4+3]=m4.w;
    __syncthreads();
    float4 m4n = m4; float2 ccn = cc;
    if (i < 15) {   // prefetch next chunk while computing this one
      const int chn = (seg*16 + i + 1)*32 + bh;
      m4n = *(const float4*)(wsM + (size_t)chn*1024 + tid*4);
      ccn = *(const float2*)(wsC + (size_t)chn*2048 + a*64 + v0 + c2);
    }
    float cn0 = cc.x, cn1 = cc.y;
    float mn0=0.f, mn1=0.f, mn2=0.f, mn3=0.f;
    for (int bb = 0; bb < 32; ++bb) {
      const float m = sMc[a*33 + bb];
      const float2 s2 = *(const float2*)(sCa + bb*18 + c2);
      cn0 += m*s2.x; cn1 += m*s2.y;
      mn0 += m*sMa[bb*33+b4+0]; mn1 += m*sMa[bb*33+b4+1];
      mn2 += m*sMa[bb*33+b4+2]; mn3 += m*sMa[bb*33+b4+3];
    }
    __syncthreads();
    sCa[a*18+c2] = cn0; sCa[a*18+c2+1] = cn1;
    sMa[a*33+b4+0]=mn0; sMa[a*33+b4+1]=mn1; sMa[a*33+b4+2]=mn2; sMa[a*33+b4+3]=mn3;
    m4 = m4n; cc = ccn;
  }
  // epilogue reads only own-written elements: no barrier needed
  const size_t sid = (size_t)(bh*8 + seg);
  float* wsMs = ws + OFF_MS;
  float* wsCs = ws + OFF_CS;
  if (vt == 0) {
    #pragma unroll
    for (int r = 0; r < 4; ++r) wsMs[sid*1024 + tid*4 + r] = sMa[a*33+b4+r];
  }
  float2 co; co.x = sCa[a*18+c2]; co.y = sCa[a*18+c2+1];
  *(float2*)(wsCs + sid*2048 + a*64 + v0 + c2) = co;
}

// ---------------- scanB: scan 8 segments per bh (V-split x4, grid 128) ----------------
__global__ __launch_bounds__(256) void kda_scanB(float* __restrict__ ws)
{
  __shared__ float sS[32*18];
  __shared__ float sM[32*33];
  const int tid = threadIdx.x;
  const int vt = blockIdx.x & 3, bh = blockIdx.x >> 2;
  const int v0 = vt*16;
  const int a = tid >> 3, b4 = (tid & 7)*4, c2 = (tid & 7)*2;
  const float* wsMs = ws + OFF_MS;
  const float* wsCs = ws + OFF_CS;
  float* wsSs = ws + OFF_SS;

  float s0 = 0.f, s1 = 0.f;
  sS[a*18 + c2] = 0.f; sS[a*18 + c2 + 1] = 0.f;
  const size_t sid0 = (size_t)(bh*8);
  float4 m4 = *(const float4*)(wsMs + sid0*1024 + tid*4);
  float2 cc = *(const float2*)(wsCs + sid0*2048 + a*64 + v0 + c2);

  for (int seg = 0; seg < 8; ++seg) {
    const size_t sid = (size_t)(bh*8 + seg);
    *(float2*)(wsSs + sid*2048 + a*64 + v0 + c2) = make_float2(s0, s1);
    sM[a*33+b4+0]=m4.x; sM[a*33+b4+1]=m4.y; sM[a*33+b4+2]=m4.z; sM[a*33+b4+3]=m4.w;
    __syncthreads();
    float4 m4n = m4; float2 ccn = cc;
    if (seg < 7) {
      m4n = *(const float4*)(wsMs + (sid+1)*1024 + tid*4);
      ccn = *(const float2*)(wsCs + (sid+1)*2048 + a*64 + v0 + c2);
    }
    float n0 = cc.x, n1 = cc.y;
    for (int bb = 0; bb < 32; ++bb) {
      const float m = sM[a*33 + bb];
      const float2 s2 = *(const float2*)(sS + bb*18 + c2);
      n0 += m*s2.x; n1 += m*s2.y;
    }
    __syncthreads();
    s0 = n0; s1 = n1;
    sS[a*18+c2] = s0; sS[a*18+c2+1] = s1;
    m4 = m4n; cc = ccn;
  }
}

// ---------------- scanC: replay chunks, write entering-S over C slot (V-split x4) ----------------
__global__ __launch_bounds__(256) void kda_scanC(float* __restrict__ ws)
{
  __shared__ float sM[32*33];
  __shared__ float sS[32*18];
  const int tid = threadIdx.x;
  const int vt = blockIdx.x & 3, seg = (blockIdx.x >> 2) & 7, bh = blockIdx.x >> 5;
  const int v0 = vt*16;
  const int a = tid >> 3, b4 = (tid & 7)*4, c2 = (tid & 7)*2;
  const float* wsM = ws + OFF_M;
  float* wsC = ws + OFF_C;
  const float* wsSs = ws + OFF_SS;

  const size_t sid = (size_t)(bh*8 + seg);
  float s0, s1;
  {
    float2 sv = *(const float2*)(wsSs + sid*2048 + a*64 + v0 + c2);
    s0 = sv.x; s1 = sv.y;
    sS[a*18 + c2] = s0; sS[a*18 + c2 + 1] = s1;
  }
  int ch = (seg*16)*32 + bh;
  float4 m4 = *(const float4*)(wsM + (size_t)ch*1024 + tid*4);
  float2 cc = *(const float2*)(wsC + (size_t)ch*2048 + a*64 + v0 + c2);

  for (int i = 0; i < 16; ++i) {
    const int chc = (seg*16 + i)*32 + bh;
    sM[a*33+b4+0]=m4.x; sM[a*33+b4+1]=m4.y; sM[a*33+b4+2]=m4.z; sM[a*33+b4+3]=m4.w;
    // entering-S over the consumed C slice (own elements; cc already in regs)
    *(float2*)(wsC + (size_t)chc*2048 + a*64 + v0 + c2) = make_float2(s0, s1);
    __syncthreads();
    float4 m4n = m4; float2 ccn = cc;
    if (i < 15) {   // prefetch next chunk's (M,C); same-thread same-address order vs next overwrite
      const int chn = (seg*16 + i + 1)*32 + bh;
      m4n = *(const float4*)(wsM + (size_t)chn*1024 + tid*4);
      ccn = *(const float2*)(wsC + (size_t)chn*2048 + a*64 + v0 + c2);
    }
    float n0 = cc.x, n1 = cc.y;
    for (int bb = 0; bb < 32; ++bb) {
      const float m = sM[a*33 + bb];
      const float2 s2 = *(const float2*)(sS + bb*18 + c2);
      n0 += m*s2.x; n1 += m*s2.y;
    }
    __syncthreads();
    s0 = n0; s1 = n1;
    sS[a*18+c2] = s0; sS[a*18+c2+1] = s1;
    m4 = m4n; cc = ccn;
  }
}

// ---------------- Phase 3: Aqk + output (o = Aqk@u + (qg - Aqk@w)@S) ----------------
__global__ __launch_bounds__(512, 4) void kda_phase3(
    const float* __restrict__ qin, const float* __restrict__ kin,
    const float* __restrict__ graw,
    const float* __restrict__ A_log, const float* __restrict__ dt_bias,
    const float* __restrict__ ws, float* __restrict__ out)
{
  __shared__ float sG[64*33];   // gcum (s33) -> S (s64, first 2048)
  __shared__ float sQ[64*33];   // qn -> qeff
  __shared__ float sA[64*65];   // Aqk
  __shared__ float sV[64*64];   // P/Qb scratch -> w (s32) -> u (s64)

  const int tid = threadIdx.x;
  const int ch = blockIdx.x;
  const int c = ch >> 5, bh = ch & 31;
  const int b = bh >> 4, h = bh & 15;
  const int t0 = c*64;
  const int iq = tid >> 3, kq = (tid & 7)*4;

  const float* wsW = ws;            // w (64x32)
  const float* wsU = ws + OFF_U;    // u (64x64)
  const float* wsS = ws + OFF_C;    // entering S (32x64) written by scanC

  const float negA = -__expf(A_log[h]);
  {
    const float* gr = graw + (((size_t)b*Tt + t0 + iq)*Hh + h)*32 + kq;
    const float* db = dt_bias + h*32 + kq;
    #pragma unroll
    for (int r = 0; r < 4; ++r)
      sG[iq*33 + kq + r] = negA * softplusf(gr[r] + db[r]);
  }
  __syncthreads();
  if (tid < 32) { // register-chunked cumsum
    float c0 = 0.f;
    for (int blk = 0; blk < 4; ++blk) {
      float v[16];
      #pragma unroll
      for (int i = 0; i < 16; ++i) v[i] = sG[(blk*16+i)*33 + tid];
      #pragma unroll
      for (int i = 0; i < 16; ++i) { c0 += v[i]; sG[(blk*16+i)*33 + tid] = c0; }
    }
  }
  float knr[4];
  { // q (l2norm * K^-1/2) into sQ; k (l2norm) in registers
    const float* qp = qin + (((size_t)b*Tt + t0 + iq)*Hh + h)*32 + kq;
    float qr[4]; float ssq = 0.f;
    #pragma unroll
    for (int r = 0; r < 4; ++r) { qr[r] = qp[r]; ssq += qr[r]*qr[r]; }
    ssq += __shfl_xor(ssq, 1); ssq += __shfl_xor(ssq, 2); ssq += __shfl_xor(ssq, 4);
    const float scq = 0.17677669529663687f / fmaxf(sqrtf(ssq), 1e-6f);
    #pragma unroll
    for (int r = 0; r < 4; ++r) sQ[iq*33 + kq + r] = qr[r]*scq;

    const float* kp = kin + (((size_t)b*Tt + t0 + iq)*Hh + h)*32 + kq;
    float ssk = 0.f;
    #pragma unroll
    for (int r = 0; r < 4; ++r) { knr[r] = kp[r]; ssk += knr[r]*knr[r]; }
    ssk += __shfl_xor(ssk, 1); ssk += __shfl_xor(ssk, 2); ssk += __shfl_xor(ssk, 4);
    const float sck = 1.f / fmaxf(sqrtf(ssk), 1e-6f);
    #pragma unroll
    for (int r = 0; r < 4; ++r) knr[r] *= sck;
  }
  __syncthreads();

  float* P  = sV;          // s33
  float* Qb = sV + 2112;   // 16x32 s32
  const int i64 = tid & 63, jj2 = (tid >> 6)*2;
  for (int jt = 0; jt < 4; ++jt) {
    const int j0 = jt*16;
    #pragma unroll
    for (int r = 0; r < 4; ++r) {
      const int idx = iq*33 + kq + r;
      P[idx] = sQ[idx] * __expf(fminf(sG[idx] - sG[j0*33 + kq + r], 0.f));
    }
    if (iq >= j0 && iq < j0 + 16) {
      const int jj = iq - j0;
      #pragma unroll
      for (int r = 0; r < 4; ++r)
        Qb[jj*32 + kq + r] = knr[r] * __expf(sG[j0*33 + kq + r] - sG[iq*33 + kq + r]);
    }
    __syncthreads();
    float a0 = 0.f, a1 = 0.f;
    for (int k8 = 0; k8 < 4; ++k8) {
      const int k0 = k8*8;
      float qa[8], qb[8];
      #pragma unroll
      for (int t4 = 0; t4 < 2; ++t4) {
        float4 xa = *(const float4*)(Qb + (jj2  )*32 + k0 + t4*4);
        float4 xb = *(const float4*)(Qb + (jj2+1)*32 + k0 + t4*4);
        qa[t4*4+0]=xa.x; qa[t4*4+1]=xa.y; qa[t4*4+2]=xa.z; qa[t4*4+3]=xa.w;
        qb[t4*4+0]=xb.x; qb[t4*4+1]=xb.y; qb[t4*4+2]=xb.z; qb[t4*4+3]=xb.w;
      }
      #pragma unroll
      for (int kk = 0; kk < 8; ++kk) {
        const float p = P[i64*33 + k0 + kk];
        a0 += p * qa[kk]; a1 += p * qb[kk];
      }
    }
    const int j_0 = j0 + jj2;
    sA[i64*65 + j_0  ] = (i64 >= j_0  ) ? a0 : 0.f;   // incl. diagonal
    sA[i64*65 + j_0+1] = (i64 >= j_0+1) ? a1 : 0.f;
    __syncthreads();
  }

  float qgr[4];
  { // qg = qn * exp(gcum) in registers (own row slice)
    #pragma unroll
    for (int r = 0; r < 4; ++r) {
      const int idx = iq*33 + kq + r;
      qgr[r] = sQ[idx] * __expf(sG[idx]);
    }
  }
  __syncthreads();   // gcum + sV scratch dead
  { // stage S into sG (s64 flat) and w into sV (s32 flat)
    *(float4*)(sG + tid*4) = *(const float4*)(wsS + (size_t)ch*2048 + tid*4);
    *(float4*)(sV + tid*4) = *(const float4*)(wsW + (size_t)ch*2048 + tid*4);
  }
  __syncthreads();
  { // qeff = qg - Aqk @ w  -> sQ
    float qe[4];
    #pragma unroll
    for (int r = 0; r < 4; ++r) qe[r] = qgr[r];
    for (int j = 0; j <= iq; ++j) {
      const float av = sA[iq*65 + j];
      const float4 w0 = *(const float4*)(sV + j*32 + kq);
      qe[0]-=av*w0.x; qe[1]-=av*w0.y; qe[2]-=av*w0.z; qe[3]-=av*w0.w;
    }
    #pragma unroll
    for (int r = 0; r < 4; ++r) sQ[iq*33 + kq + r] = qe[r];
  }
  __syncthreads();   // qeff visible; sV-w reads done
  { // stage u into sV (s64)
    #pragma unroll
    for (int rr = 0; rr < 2; ++rr) {
      const int f = tid + 512*rr;
      *(float4*)(sV + f*4) = *(const float4*)(wsU + (size_t)ch*4096 + f*4);
    }
  }
  __syncthreads();
  { // o = qeff @ S + Aqk @ u
    const int vs = (tid & 7)*8;
    float acc[8];
    #pragma unroll
    for (int r = 0; r < 8; ++r) acc[r] = 0.f;
    for (int kk = 0; kk < 32; ++kk) {
      const float qv = sQ[iq*33 + kk];
      const float4 s0 = *(const float4*)(sG + kk*64 + vs);
      const float4 s1 = *(const float4*)(sG + kk*64 + vs + 4);
      acc[0]+=qv*s0.x; acc[1]+=qv*s0.y; acc[2]+=qv*s0.z; acc[3]+=qv*s0.w;
      acc[4]+=qv*s1.x; acc[5]+=qv*s1.y; acc[6]+=qv*s1.z; acc[7]+=qv*s1.w;
    }
    for (int j = 0; j <= iq; ++j) {
      const float av = sA[iq*65 + j];
      const float4 u0 = *(const float4*)(sV + j*64 + vs);
      const float4 u1 = *(const float4*)(sV + j*64 + vs + 4);
      acc[0]+=av*u0.x; acc[1]+=av*u0.y; acc[2]+=av*u0.z; acc[3]+=av*u0.w;
      acc[4]+=av*u1.x; acc[5]+=av*u1.y; acc[6]+=av*u1.z; acc[7]+=av*u1.w;
    }
    float* op = out + (((size_t)b*Tt + t0 + iq)*Hh + h)*64 + vs;
    *(float4*)(op)     = make_float4(acc[0],acc[1],acc[2],acc[3]);
    *(float4*)(op + 4) = make_float4(acc[4],acc[5],acc[6],acc[7]);
  }
}

extern "C" void kernel_launch(void* const* d_in, const int* in_sizes, int n_in,
                              void* d_out, int out_size, void* d_ws, size_t ws_size,
                              hipStream_t stream) {
  const float* q    = (const float*)d_in[0];
  const float* k    = (const float*)d_in[1];
  const float* v    = (const float*)d_in[2];
  const float* graw = (const float*)d_in[3];
  const float* beta = (const float*)d_in[4];
  const float* A_log= (const float*)d_in[5];
  const float* dtb  = (const float*)d_in[6];
  float* out = (float*)d_out;
  float* ws  = (float*)d_ws;
  // requires ws_size >= 156.3 MB

  kda_phase1<<<NCH, 512, 0, stream>>>(k, v, graw, beta, A_log, dtb, ws);
  kda_scanA<<<1024, 256, 0, stream>>>(ws);
  kda_scanB<<<128, 256, 0, stream>>>(ws);
  kda_scanC<<<1024, 256, 0, stream>>>(ws);
  kda_phase3<<<NCH, 512, 0, stream>>>(q, k, graw, A_log, dtb, ws, out);
}

// Round 3
// 1178.355 us; speedup vs baseline: 1.5713x; 1.5309x over previous
//
#include <hip/hip_runtime.h>
#include <math.h>

// Problem constants (B,T,H,K,V,BT) = (2,8192,16,32,64,64)
#define Tt 8192
#define Hh 16
#define NCH 4096        // chunk-heads, ch = c*32 + (b*16+h)
// Workspace layout (floats):
//   wsW  [NCH][2048]  w (64x32 row-major)
//   wsU  [NCH][4096]  u (64x64 row-major)
//   wsM  [NCH][1024]  M = diag(egl) - Kd^T W
//   wsC  [NCH][2048]  C = Kd^T U   -> overwritten by entering-S (32x64) in scanC
//   wsMs [256][1024]  per-segment composed M
//   wsCs [256][2048]  per-segment composed C
//   wsSs [256][2048]  entering S per segment
// total = (4096*9216 + 256*5120)*4 B = 156.3 MB

#define OFF_U   ((size_t)NCH*2048)
#define OFF_M   ((size_t)NCH*6144)
#define OFF_C   ((size_t)NCH*7168)
#define OFF_MS  ((size_t)NCH*9216)
#define OFF_CS  (OFF_MS + (size_t)256*1024)
#define OFF_SS  (OFF_CS + (size_t)256*2048)

__device__ __forceinline__ float softplusf(float x) {
  return fmaxf(x, 0.f) + log1pf(__expf(-fabsf(x)));
}

// ---------------- Phase 1: per-chunk intra quantities + (M,C) ----------------
// 512 threads/chunk. LDS 52KB/block.
// NO min-waves clause: R1 (512,6)->VGPR 40 + 5.8GB spill; R2 (512,4)->VGPR 64 +
// 4.7GB spill. The clause acts as an allocator TARGET and forces spills below the
// ~90-VGPR natural live set. Plain (512) caps at 256 -> no spill pressure.
__global__ __launch_bounds__(512) void kda_phase1(
    const float* __restrict__ kin, const float* __restrict__ vin,
    const float* __restrict__ graw, const float* __restrict__ beta,
    const float* __restrict__ A_log, const float* __restrict__ dt_bias,
    float* __restrict__ ws)
{
  __shared__ float sG[64*33];   // gcum (s33) -> w (s32, first 2048)
  __shared__ float sK[64*33];   // kn -> kd (s33)
  __shared__ float sL[64*64];   // L col-major -> k_egb(s32) -> vb(s64) -> u(s64)
  __shared__ float sT[64*65];   // P(s33)+Qb(16x32 @2112) -> Tm (s65)
  __shared__ float sC2[2*272];  // per-group off-diag temp
  __shared__ float sEgl[32];

  const int tid = threadIdx.x;
  const int ch = blockIdx.x;
  const int c = ch >> 5, bh = ch & 31;
  const int b = bh >> 4, h = bh & 15;
  const int t0 = c*64;
  const int iq = tid >> 3, kq = (tid & 7)*4;

  float* wsW = ws;
  float* wsU = ws + OFF_U;
  float* wsM = ws + OFF_M;
  float* wsCc= ws + OFF_C;

  const float negA = -__expf(A_log[h]);

  { // gate g into sG (4 elems/thread)
    const float* gr = graw + (((size_t)b*Tt + t0 + iq)*Hh + h)*32 + kq;
    const float* db = dt_bias + h*32 + kq;
    #pragma unroll
    for (int r = 0; r < 4; ++r)
      sG[iq*33 + kq + r] = negA * softplusf(gr[r] + db[r]);
  }
  __syncthreads();
  if (tid < 32) { // cumsum over time per k, register-chunked (pipelined loads)
    float c0 = 0.f;
    for (int blk = 0; blk < 4; ++blk) {
      float v[16];
      #pragma unroll
      for (int i = 0; i < 16; ++i) v[i] = sG[(blk*16+i)*33 + tid];
      #pragma unroll
      for (int i = 0; i < 16; ++i) { c0 += v[i]; sG[(blk*16+i)*33 + tid] = c0; }
    }
  }
  { // k row-l2-normalize into sK (8 threads/row)
    const float* kp = kin + (((size_t)b*Tt + t0 + iq)*Hh + h)*32 + kq;
    float kr[4]; float ss = 0.f;
    #pragma unroll
    for (int r = 0; r < 4; ++r) { kr[r] = kp[r]; ss += kr[r]*kr[r]; }
    ss += __shfl_xor(ss, 1); ss += __shfl_xor(ss, 2); ss += __shfl_xor(ss, 4);
    const float sc = 1.f / fmaxf(sqrtf(ss), 1e-6f);
    #pragma unroll
    for (int r = 0; r < 4; ++r) sK[iq*33 + kq + r] = kr[r]*sc;
  }
  __syncthreads();

  // ---- Akk in 16-column tiles (4 tiles, 8 barriers total) ----
  const float b_cm = beta[((size_t)b*Tt + t0 + (tid & 63))*Hh + h];
  float* P  = sT;          // 64x32 s33
  float* Qb = sT + 2112;   // 16x32 s32
  const int i64 = tid & 63, jj2 = (tid >> 6)*2;
  for (int jt = 0; jt < 4; ++jt) {
    const int j0 = jt*16;
    #pragma unroll
    for (int r = 0; r < 4; ++r) {
      const int idx = iq*33 + kq + r;
      P[idx] = sK[idx] * __expf(fminf(sG[idx] - sG[j0*33 + kq + r], 0.f));
    }
    {
      const int jj = tid >> 5, kk = tid & 31;
      Qb[jj*32 + kk] = sK[(j0+jj)*33 + kk] * __expf(sG[j0*33 + kk] - sG[(j0+jj)*33 + kk]);
    }
    __syncthreads();
    float a0 = 0.f, a1 = 0.f;
    for (int k8 = 0; k8 < 4; ++k8) {   // k in chunks of 8: bounded reg pressure
      const int k0 = k8*8;
      float qa[8], qb[8];
      #pragma unroll
      for (int t4 = 0; t4 < 2; ++t4) {
        float4 xa = *(const float4*)(Qb + (jj2  )*32 + k0 + t4*4);
        float4 xb = *(const float4*)(Qb + (jj2+1)*32 + k0 + t4*4);
        qa[t4*4+0]=xa.x; qa[t4*4+1]=xa.y; qa[t4*4+2]=xa.z; qa[t4*4+3]=xa.w;
        qb[t4*4+0]=xb.x; qb[t4*4+1]=xb.y; qb[t4*4+2]=xb.z; qb[t4*4+3]=xb.w;
      }
      #pragma unroll
      for (int kk = 0; kk < 8; ++kk) {
        const float p = P[i64*33 + k0 + kk];
        a0 += p * qa[kk]; a1 += p * qb[kk];
      }
    }
    const int j_0 = j0 + jj2;
    sL[(j_0  )*64 + i64] = (i64 > j_0  ) ? a0*b_cm : 0.f;
    sL[(j_0+1)*64 + i64] = (i64 > j_0+1) ? a1*b_cm : 0.f;
    __syncthreads();
  }

  // ---- Tm = (I + L)^-1, blocked 16x16 forward substitution ----
  for (int e = tid; e < 4096; e += 512) {
    const int row = e >> 6, col = e & 63;
    sT[row*65 + col] = (row == col) ? 1.f : 0.f;
  }
  __syncthreads();
  // diagonal blocks: all cross-iteration deps are lane-local -> no barriers
  if (tid < 64) {
    const int p = tid >> 4, col = tid & 15;
    for (int i = 1; i < 16; ++i) {
      const int gi = p*16 + i, gc = p*16 + col;
      float acc = 0.f;
      for (int j = 0; j < i; ++j)
        acc -= sL[(p*16+j)*64 + gi] * sT[(p*16+j)*65 + gc];
      sT[gi*65 + gc] = acc + ((i == col) ? 1.f : 0.f);
    }
  }
  __syncthreads();
  // off-diagonal blocks: 2 groups x 256 threads (1 elem/thread), 3 rounds
  {
    const int grp = tid >> 8, gl = tid & 255;
    const int ri = gl & 15, cc = gl >> 4;
    auto offblk1 = [&](int p, int q) {
      float acc = 0.f;
      for (int m = q; m < p; ++m) {
        #pragma unroll
        for (int j = 0; j < 16; ++j)
          acc += sL[(m*16+j)*64 + p*16+ri] * sT[(m*16+j)*65 + q*16+cc];
      }
      sC2[grp*272 + ri*17 + cc] = acc;
    };
    auto offblk2 = [&](int p, int q) {
      float bacc = 0.f;
      #pragma unroll
      for (int j = 0; j < 16; ++j)
        bacc += sT[(p*16+ri)*65 + p*16 + j] * sC2[grp*272 + j*17 + cc];
      sT[(p*16+ri)*65 + q*16+cc] = -bacc;
    };
    int p = grp ? 2 : 1, q = grp ? 1 : 0;          // r1: (1,0) | (2,1)
    offblk1(p,q); __syncthreads(); offblk2(p,q); __syncthreads();
    p = grp ? 3 : 2; q = grp ? 2 : 0;              // r2: (2,0) | (3,2)
    offblk1(p,q); __syncthreads(); offblk2(p,q); __syncthreads();
    p = 3; q = grp ? 1 : 0;                        // r3: (3,0) | (3,1)
    offblk1(p,q); __syncthreads(); offblk2(p,q); __syncthreads();
  }

  { // k_egb (s32 into sL[0..2047]); kd overwrites sK (s33); egl
    const float b_row = beta[((size_t)b*Tt + t0 + iq)*Hh + h];
    #pragma unroll
    for (int r = 0; r < 4; ++r) {
      const int idx = iq*33 + kq + r;
      const float g = sG[idx], kn = sK[idx];
      sL[iq*32 + kq + r] = b_row * kn * __expf(g);
      sK[idx] = kn * __expf(sG[63*33 + kq + r] - g);
    }
    if (tid < 32) sEgl[tid] = __expf(sG[63*33 + tid]);
  }
  __syncthreads();

  { // w = Tm @ k_egb -> global + sG (s32; gcum dead)
    float acc[4] = {0.f,0.f,0.f,0.f};
    for (int j = 0; j <= iq; ++j) {
      const float t = sT[iq*65 + j];
      const float4 e0 = *(const float4*)(sL + j*32 + kq);
      acc[0]+=t*e0.x; acc[1]+=t*e0.y; acc[2]+=t*e0.z; acc[3]+=t*e0.w;
    }
    float4 o4; o4.x=acc[0]; o4.y=acc[1]; o4.z=acc[2]; o4.w=acc[3];
    *(float4*)(wsW + (size_t)ch*2048 + tid*4) = o4;
    *(float4*)(sG + tid*4) = o4;
  }
  __syncthreads();

  { // vb = beta_j * v into sL (s64)
    #pragma unroll
    for (int r = 0; r < 2; ++r) {
      const int f = tid + 512*r;
      const int j = f >> 4, qd = f & 15;
      const float bj = beta[((size_t)b*Tt + t0 + j)*Hh + h];
      float4 v4 = *(const float4*)(vin + (((size_t)b*Tt + t0 + j)*Hh + h)*64 + qd*4);
      v4.x *= bj; v4.y *= bj; v4.z *= bj; v4.w *= bj;
      *(float4*)(sL + j*64 + qd*4) = v4;
    }
  }
  __syncthreads();

  float uacc[8];
  { // u = Tm @ vb -> wsU (and regs)
    const int vs = (tid & 7)*8;
    #pragma unroll
    for (int r = 0; r < 8; ++r) uacc[r] = 0.f;
    for (int j = 0; j <= iq; ++j) {
      const float t = sT[iq*65 + j];
      const float4 e0 = *(const float4*)(sL + j*64 + vs);
      const float4 e1 = *(const float4*)(sL + j*64 + vs + 4);
      uacc[0]+=t*e0.x; uacc[1]+=t*e0.y; uacc[2]+=t*e0.z; uacc[3]+=t*e0.w;
      uacc[4]+=t*e1.x; uacc[5]+=t*e1.y; uacc[6]+=t*e1.z; uacc[7]+=t*e1.w;
    }
    #pragma unroll
    for (int rr = 0; rr < 2; ++rr) {
      float4 o4; o4.x=uacc[rr*4]; o4.y=uacc[rr*4+1]; o4.z=uacc[rr*4+2]; o4.w=uacc[rr*4+3];
      *(float4*)(wsU + (size_t)ch*4096 + tid*8 + rr*4) = o4;
    }
  }
  __syncthreads();       // all vb reads done
  { // u into sL (s64)
    const int vs = (tid & 7)*8;
    #pragma unroll
    for (int rr = 0; rr < 2; ++rr) {
      float4 o4; o4.x=uacc[rr*4]; o4.y=uacc[rr*4+1]; o4.z=uacc[rr*4+2]; o4.w=uacc[rr*4+3];
      *(float4*)(sL + iq*64 + vs + rr*4) = o4;
    }
  }
  __syncthreads();

  { // M = diag(egl) - Kd^T W ; C = Kd^T U  (16 threads per output row a)
    const int a = tid >> 4, b2 = (tid & 15)*2, v4 = (tid & 15)*4;
    float mA[2] = {0.f, 0.f};
    float cA[4] = {0.f, 0.f, 0.f, 0.f};
    for (int t = 0; t < 64; ++t) {
      const float kd = sK[t*33 + a];
      const float2 wv = *(const float2*)(sG + t*32 + b2);
      mA[0]+=kd*wv.x; mA[1]+=kd*wv.y;
      const float4 u0 = *(const float4*)(sL + t*64 + v4);
      cA[0]+=kd*u0.x; cA[1]+=kd*u0.y; cA[2]+=kd*u0.z; cA[3]+=kd*u0.w;
    }
    float2 m2;
    m2.x = ((a == b2  ) ? sEgl[a] : 0.f) - mA[0];
    m2.y = ((a == b2+1) ? sEgl[a] : 0.f) - mA[1];
    *(float2*)(wsM + (size_t)ch*1024 + tid*2) = m2;
    float4 c4; c4.x=cA[0]; c4.y=cA[1]; c4.z=cA[2]; c4.w=cA[3];
    *(float4*)(wsCc + (size_t)ch*2048 + tid*4) = c4;
  }
}

// ---------------- scanA: compose 16 chunk maps per segment (V-split x4) ----------------
// 1-deep HBM prefetch; 2 barriers/iteration.
__global__ __launch_bounds__(256) void kda_scanA(float* __restrict__ ws)
{
  __shared__ float sMa[32*33];
  __shared__ float sMc[32*33];
  __shared__ float sCa[32*18];
  const int tid = threadIdx.x;
  const int vt = blockIdx.x & 3, seg = (blockIdx.x >> 2) & 7, bh = blockIdx.x >> 5;
  const int v0 = vt*16;
  const int a = tid >> 3, b4 = (tid & 7)*4, c2 = (tid & 7)*2;
  const float* wsM = ws + OFF_M;
  const float* wsC = ws + OFF_C;

  #pragma unroll
  for (int r = 0; r < 4; ++r) sMa[a*33 + b4 + r] = (a == b4 + r) ? 1.f : 0.f;
  sCa[a*18 + c2] = 0.f; sCa[a*18 + c2 + 1] = 0.f;

  int ch = (seg*16)*32 + bh;
  float4 m4 = *(const float4*)(wsM + (size_t)ch*1024 + tid*4);
  float2 cc = *(const float2*)(wsC + (size_t)ch*2048 + a*64 + v0 + c2);

  for (int i = 0; i < 16; ++i) {
    sMc[a*33+b4+0]=m4.x; sMc[a*33+b4+1]=m4.y; sMc[a*33+b4+2]=m4.z; sMc[a*33+b4+3]=m4.w;
    __syncthreads();
    float4 m4n = m4; float2 ccn = cc;
    if (i < 15) {   // prefetch next chunk while computing this one
      const int chn = (seg*16 + i + 1)*32 + bh;
      m4n = *(const float4*)(wsM + (size_t)chn*1024 + tid*4);
      ccn = *(const float2*)(wsC + (size_t)chn*2048 + a*64 + v0 + c2);
    }
    float cn0 = cc.x, cn1 = cc.y;
    float mn0=0.f, mn1=0.f, mn2=0.f, mn3=0.f;
    for (int bb = 0; bb < 32; ++bb) {
      const float m = sMc[a*33 + bb];
      const float2 s2 = *(const float2*)(sCa + bb*18 + c2);
      cn0 += m*s2.x; cn1 += m*s2.y;
      mn0 += m*sMa[bb*33+b4+0]; mn1 += m*sMa[bb*33+b4+1];
      mn2 += m*sMa[bb*33+b4+2]; mn3 += m*sMa[bb*33+b4+3];
    }
    __syncthreads();
    sCa[a*18+c2] = cn0; sCa[a*18+c2+1] = cn1;
    sMa[a*33+b4+0]=mn0; sMa[a*33+b4+1]=mn1; sMa[a*33+b4+2]=mn2; sMa[a*33+b4+3]=mn3;
    m4 = m4n; cc = ccn;
  }
  // epilogue reads only own-written elements: no barrier needed
  const size_t sid = (size_t)(bh*8 + seg);
  float* wsMs = ws + OFF_MS;
  float* wsCs = ws + OFF_CS;
  if (vt == 0) {
    #pragma unroll
    for (int r = 0; r < 4; ++r) wsMs[sid*1024 + tid*4 + r] = sMa[a*33+b4+r];
  }
  float2 co; co.x = sCa[a*18+c2]; co.y = sCa[a*18+c2+1];
  *(float2*)(wsCs + sid*2048 + a*64 + v0 + c2) = co;
}

// ---------------- scanB: scan 8 segments per bh (V-split x4, grid 128) ----------------
__global__ __launch_bounds__(256) void kda_scanB(float* __restrict__ ws)
{
  __shared__ float sS[32*18];
  __shared__ float sM[32*33];
  const int tid = threadIdx.x;
  const int vt = blockIdx.x & 3, bh = blockIdx.x >> 2;
  const int v0 = vt*16;
  const int a = tid >> 3, b4 = (tid & 7)*4, c2 = (tid & 7)*2;
  const float* wsMs = ws + OFF_MS;
  const float* wsCs = ws + OFF_CS;
  float* wsSs = ws + OFF_SS;

  float s0 = 0.f, s1 = 0.f;
  sS[a*18 + c2] = 0.f; sS[a*18 + c2 + 1] = 0.f;
  const size_t sid0 = (size_t)(bh*8);
  float4 m4 = *(const float4*)(wsMs + sid0*1024 + tid*4);
  float2 cc = *(const float2*)(wsCs + sid0*2048 + a*64 + v0 + c2);

  for (int seg = 0; seg < 8; ++seg) {
    const size_t sid = (size_t)(bh*8 + seg);
    *(float2*)(wsSs + sid*2048 + a*64 + v0 + c2) = make_float2(s0, s1);
    sM[a*33+b4+0]=m4.x; sM[a*33+b4+1]=m4.y; sM[a*33+b4+2]=m4.z; sM[a*33+b4+3]=m4.w;
    __syncthreads();
    float4 m4n = m4; float2 ccn = cc;
    if (seg < 7) {
      m4n = *(const float4*)(wsMs + (sid+1)*1024 + tid*4);
      ccn = *(const float2*)(wsCs + (sid+1)*2048 + a*64 + v0 + c2);
    }
    float n0 = cc.x, n1 = cc.y;
    for (int bb = 0; bb < 32; ++bb) {
      const float m = sM[a*33 + bb];
      const float2 s2 = *(const float2*)(sS + bb*18 + c2);
      n0 += m*s2.x; n1 += m*s2.y;
    }
    __syncthreads();
    s0 = n0; s1 = n1;
    sS[a*18+c2] = s0; sS[a*18+c2+1] = s1;
    m4 = m4n; cc = ccn;
  }
}

// ---------------- scanC: replay chunks, write entering-S over C slot (V-split x4) ----------------
__global__ __launch_bounds__(256) void kda_scanC(float* __restrict__ ws)
{
  __shared__ float sM[32*33];
  __shared__ float sS[32*18];
  const int tid = threadIdx.x;
  const int vt = blockIdx.x & 3, seg = (blockIdx.x >> 2) & 7, bh = blockIdx.x >> 5;
  const int v0 = vt*16;
  const int a = tid >> 3, b4 = (tid & 7)*4, c2 = (tid & 7)*2;
  const float* wsM = ws + OFF_M;
  float* wsC = ws + OFF_C;
  const float* wsSs = ws + OFF_SS;

  const size_t sid = (size_t)(bh*8 + seg);
  float s0, s1;
  {
    float2 sv = *(const float2*)(wsSs + sid*2048 + a*64 + v0 + c2);
    s0 = sv.x; s1 = sv.y;
    sS[a*18 + c2] = s0; sS[a*18 + c2 + 1] = s1;
  }
  int ch = (seg*16)*32 + bh;
  float4 m4 = *(const float4*)(wsM + (size_t)ch*1024 + tid*4);
  float2 cc = *(const float2*)(wsC + (size_t)ch*2048 + a*64 + v0 + c2);

  for (int i = 0; i < 16; ++i) {
    const int chc = (seg*16 + i)*32 + bh;
    sM[a*33+b4+0]=m4.x; sM[a*33+b4+1]=m4.y; sM[a*33+b4+2]=m4.z; sM[a*33+b4+3]=m4.w;
    // entering-S over the consumed C slice (own elements; cc already in regs)
    *(float2*)(wsC + (size_t)chc*2048 + a*64 + v0 + c2) = make_float2(s0, s1);
    __syncthreads();
    float4 m4n = m4; float2 ccn = cc;
    if (i < 15) {   // prefetch next chunk's (M,C); same-thread same-address order vs next overwrite
      const int chn = (seg*16 + i + 1)*32 + bh;
      m4n = *(const float4*)(wsM + (size_t)chn*1024 + tid*4);
      ccn = *(const float2*)(wsC + (size_t)chn*2048 + a*64 + v0 + c2);
    }
    float n0 = cc.x, n1 = cc.y;
    for (int bb = 0; bb < 32; ++bb) {
      const float m = sM[a*33 + bb];
      const float2 s2 = *(const float2*)(sS + bb*18 + c2);
      n0 += m*s2.x; n1 += m*s2.y;
    }
    __syncthreads();
    s0 = n0; s1 = n1;
    sS[a*18+c2] = s0; sS[a*18+c2+1] = s1;
    m4 = m4n; cc = ccn;
  }
}

// ---------------- Phase 3: Aqk + output (o = Aqk@u + (qg - Aqk@w)@S) ----------------
__global__ __launch_bounds__(512) void kda_phase3(
    const float* __restrict__ qin, const float* __restrict__ kin,
    const float* __restrict__ graw,
    const float* __restrict__ A_log, const float* __restrict__ dt_bias,
    const float* __restrict__ ws, float* __restrict__ out)
{
  __shared__ float sG[64*33];   // gcum (s33) -> S (s64, first 2048)
  __shared__ float sQ[64*33];   // qn -> qeff
  __shared__ float sA[64*65];   // Aqk
  __shared__ float sV[64*64];   // P/Qb scratch -> w (s32) -> u (s64)

  const int tid = threadIdx.x;
  const int ch = blockIdx.x;
  const int c = ch >> 5, bh = ch & 31;
  const int b = bh >> 4, h = bh & 15;
  const int t0 = c*64;
  const int iq = tid >> 3, kq = (tid & 7)*4;

  const float* wsW = ws;            // w (64x32)
  const float* wsU = ws + OFF_U;    // u (64x64)
  const float* wsS = ws + OFF_C;    // entering S (32x64) written by scanC

  const float negA = -__expf(A_log[h]);
  {
    const float* gr = graw + (((size_t)b*Tt + t0 + iq)*Hh + h)*32 + kq;
    const float* db = dt_bias + h*32 + kq;
    #pragma unroll
    for (int r = 0; r < 4; ++r)
      sG[iq*33 + kq + r] = negA * softplusf(gr[r] + db[r]);
  }
  __syncthreads();
  if (tid < 32) { // register-chunked cumsum
    float c0 = 0.f;
    for (int blk = 0; blk < 4; ++blk) {
      float v[16];
      #pragma unroll
      for (int i = 0; i < 16; ++i) v[i] = sG[(blk*16+i)*33 + tid];
      #pragma unroll
      for (int i = 0; i < 16; ++i) { c0 += v[i]; sG[(blk*16+i)*33 + tid] = c0; }
    }
  }
  float knr[4];
  { // q (l2norm * K^-1/2) into sQ; k (l2norm) in registers
    const float* qp = qin + (((size_t)b*Tt + t0 + iq)*Hh + h)*32 + kq;
    float qr[4]; float ssq = 0.f;
    #pragma unroll
    for (int r = 0; r < 4; ++r) { qr[r] = qp[r]; ssq += qr[r]*qr[r]; }
    ssq += __shfl_xor(ssq, 1); ssq += __shfl_xor(ssq, 2); ssq += __shfl_xor(ssq, 4);
    const float scq = 0.17677669529663687f / fmaxf(sqrtf(ssq), 1e-6f);
    #pragma unroll
    for (int r = 0; r < 4; ++r) sQ[iq*33 + kq + r] = qr[r]*scq;

    const float* kp = kin + (((size_t)b*Tt + t0 + iq)*Hh + h)*32 + kq;
    float ssk = 0.f;
    #pragma unroll
    for (int r = 0; r < 4; ++r) { knr[r] = kp[r]; ssk += knr[r]*knr[r]; }
    ssk += __shfl_xor(ssk, 1); ssk += __shfl_xor(ssk, 2); ssk += __shfl_xor(ssk, 4);
    const float sck = 1.f / fmaxf(sqrtf(ssk), 1e-6f);
    #pragma unroll
    for (int r = 0; r < 4; ++r) knr[r] *= sck;
  }
  __syncthreads();

  float* P  = sV;          // s33
  float* Qb = sV + 2112;   // 16x32 s32
  const int i64 = tid & 63, jj2 = (tid >> 6)*2;
  for (int jt = 0; jt < 4; ++jt) {
    const int j0 = jt*16;
    #pragma unroll
    for (int r = 0; r < 4; ++r) {
      const int idx = iq*33 + kq + r;
      P[idx] = sQ[idx] * __expf(fminf(sG[idx] - sG[j0*33 + kq + r], 0.f));
    }
    if (iq >= j0 && iq < j0 + 16) {
      const int jj = iq - j0;
      #pragma unroll
      for (int r = 0; r < 4; ++r)
        Qb[jj*32 + kq + r] = knr[r] * __expf(sG[j0*33 + kq + r] - sG[iq*33 + kq + r]);
    }
    __syncthreads();
    float a0 = 0.f, a1 = 0.f;
    for (int k8 = 0; k8 < 4; ++k8) {
      const int k0 = k8*8;
      float qa[8], qb[8];
      #pragma unroll
      for (int t4 = 0; t4 < 2; ++t4) {
        float4 xa = *(const float4*)(Qb + (jj2  )*32 + k0 + t4*4);
        float4 xb = *(const float4*)(Qb + (jj2+1)*32 + k0 + t4*4);
        qa[t4*4+0]=xa.x; qa[t4*4+1]=xa.y; qa[t4*4+2]=xa.z; qa[t4*4+3]=xa.w;
        qb[t4*4+0]=xb.x; qb[t4*4+1]=xb.y; qb[t4*4+2]=xb.z; qb[t4*4+3]=xb.w;
      }
      #pragma unroll
      for (int kk = 0; kk < 8; ++kk) {
        const float p = P[i64*33 + k0 + kk];
        a0 += p * qa[kk]; a1 += p * qb[kk];
      }
    }
    const int j_0 = j0 + jj2;
    sA[i64*65 + j_0  ] = (i64 >= j_0  ) ? a0 : 0.f;   // incl. diagonal
    sA[i64*65 + j_0+1] = (i64 >= j_0+1) ? a1 : 0.f;
    __syncthreads();
  }

  float qgr[4];
  { // qg = qn * exp(gcum) in registers (own row slice)
    #pragma unroll
    for (int r = 0; r < 4; ++r) {
      const int idx = iq*33 + kq + r;
      qgr[r] = sQ[idx] * __expf(sG[idx]);
    }
  }
  __syncthreads();   // gcum + sV scratch dead
  { // stage S into sG (s64 flat) and w into sV (s32 flat)
    *(float4*)(sG + tid*4) = *(const float4*)(wsS + (size_t)ch*2048 + tid*4);
    *(float4*)(sV + tid*4) = *(const float4*)(wsW + (size_t)ch*2048 + tid*4);
  }
  __syncthreads();
  { // qeff = qg - Aqk @ w  -> sQ
    float qe[4];
    #pragma unroll
    for (int r = 0; r < 4; ++r) qe[r] = qgr[r];
    for (int j = 0; j <= iq; ++j) {
      const float av = sA[iq*65 + j];
      const float4 w0 = *(const float4*)(sV + j*32 + kq);
      qe[0]-=av*w0.x; qe[1]-=av*w0.y; qe[2]-=av*w0.z; qe[3]-=av*w0.w;
    }
    #pragma unroll
    for (int r = 0; r < 4; ++r) sQ[iq*33 + kq + r] = qe[r];
  }
  __syncthreads();   // qeff visible; sV-w reads done
  { // stage u into sV (s64)
    #pragma unroll
    for (int rr = 0; rr < 2; ++rr) {
      const int f = tid + 512*rr;
      *(float4*)(sV + f*4) = *(const float4*)(wsU + (size_t)ch*4096 + f*4);
    }
  }
  __syncthreads();
  { // o = qeff @ S + Aqk @ u
    const int vs = (tid & 7)*8;
    float acc[8];
    #pragma unroll
    for (int r = 0; r < 8; ++r) acc[r] = 0.f;
    for (int kk = 0; kk < 32; ++kk) {
      const float qv = sQ[iq*33 + kk];
      const float4 s0 = *(const float4*)(sG + kk*64 + vs);
      const float4 s1 = *(const float4*)(sG + kk*64 + vs + 4);
      acc[0]+=qv*s0.x; acc[1]+=qv*s0.y; acc[2]+=qv*s0.z; acc[3]+=qv*s0.w;
      acc[4]+=qv*s1.x; acc[5]+=qv*s1.y; acc[6]+=qv*s1.z; acc[7]+=qv*s1.w;
    }
    for (int j = 0; j <= iq; ++j) {
      const float av = sA[iq*65 + j];
      const float4 u0 = *(const float4*)(sV + j*64 + vs);
      const float4 u1 = *(const float4*)(sV + j*64 + vs + 4);
      acc[0]+=av*u0.x; acc[1]+=av*u0.y; acc[2]+=av*u0.z; acc[3]+=av*u0.w;
      acc[4]+=av*u1.x; acc[5]+=av*u1.y; acc[6]+=av*u1.z; acc[7]+=av*u1.w;
    }
    float* op = out + (((size_t)b*Tt + t0 + iq)*Hh + h)*64 + vs;
    *(float4*)(op)     = make_float4(acc[0],acc[1],acc[2],acc[3]);
    *(float4*)(op + 4) = make_float4(acc[4],acc[5],acc[6],acc[7]);
  }
}

extern "C" void kernel_launch(void* const* d_in, const int* in_sizes, int n_in,
                              void* d_out, int out_size, void* d_ws, size_t ws_size,
                              hipStream_t stream) {
  const float* q    = (const float*)d_in[0];
  const float* k    = (const float*)d_in[1];
  const float* v    = (const float*)d_in[2];
  const float* graw = (const float*)d_in[3];
  const float* beta = (const float*)d_in[4];
  const float* A_log= (const float*)d_in[5];
  const float* dtb  = (const float*)d_in[6];
  float* out = (float*)d_out;
  float* ws  = (float*)d_ws;
  // requires ws_size >= 156.3 MB

  kda_phase1<<<NCH, 512, 0, stream>>>(k, v, graw, beta, A_log, dtb, ws);
  kda_scanA<<<1024, 256, 0, stream>>>(ws);
  kda_scanB<<<128, 256, 0, stream>>>(ws);
  kda_scanC<<<1024, 256, 0, stream>>>(ws);
  kda_phase3<<<NCH, 512, 0, stream>>>(q, k, graw, A_log, dtb, ws, out);
}

// Round 4
// 557.142 us; speedup vs baseline: 3.3233x; 2.1150x over previous
//
#include <hip/hip_runtime.h>
#include <math.h>

// Problem constants (B,T,H,K,V,BT) = (2,8192,16,32,64,64)
#define Tt 8192
#define Hh 16
#define NCH 4096        // chunk-heads, ch = c*32 + (b*16+h)
// Workspace layout (floats):
//   wsW  [NCH][2048]  w (64x32 row-major)
//   wsU  [NCH][4096]  u (64x64 row-major)
//   wsM  [NCH][1024]  M = diag(egl) - Kd^T W
//   wsC  [NCH][2048]  C = Kd^T U   -> overwritten by entering-S (32x64) in scanC
//   wsMs [256][1024]  per-segment composed M
//   wsCs [256][2048]  per-segment composed C
//   wsSs [256][2048]  entering S per segment
// total = (4096*9216 + 256*5120)*4 B = 156.3 MB

#define OFF_U   ((size_t)NCH*2048)
#define OFF_M   ((size_t)NCH*6144)
#define OFF_C   ((size_t)NCH*7168)
#define OFF_MS  ((size_t)NCH*9216)
#define OFF_CS  (OFF_MS + (size_t)256*1024)
#define OFF_SS  (OFF_CS + (size_t)256*2048)

__device__ __forceinline__ float softplusf(float x) {
  return fmaxf(x, 0.f) + log1pf(__expf(-fabsf(x)));
}

// ---------------- Phase 1: per-chunk intra quantities + (M,C) ----------------
// 256 threads/chunk (R0-proven: VGPR 68, zero spill, 221us). 512-thread variants
// spill unavoidably (R1-R3: allocator caps at 256/min_waves VGPRs for 512t blocks).
// New vs R0: P-buffer stride 36 (float4-aligned -> ds_read_b128 in Akk hot loop),
// register-chunked cumsum (kills 64-step serial LDS dependency chain).
__global__ __launch_bounds__(256) void kda_phase1(
    const float* __restrict__ kin, const float* __restrict__ vin,
    const float* __restrict__ graw, const float* __restrict__ beta,
    const float* __restrict__ A_log, const float* __restrict__ dt_bias,
    float* __restrict__ ws)
{
  __shared__ float sG[64*33];   // gcum (s33) -> W (s32, first 2048)
  __shared__ float sK[64*33];   // kn -> kd (s33)
  __shared__ float sL[64*64];   // L col-major -> k_egb(s32) -> vb(s64) -> u(s64)
  __shared__ float sT[64*65];   // P(s36)+Qb(8x32 @2304) -> Tm (s65)
  __shared__ float sC2[3*272];  // per-wave off-diag temp
  __shared__ float sEgl[32];

  const int tid = threadIdx.x;
  const int ch = blockIdx.x;
  const int c = ch >> 5, bh = ch & 31;
  const int b = bh >> 4, h = bh & 15;
  const int t0 = c*64;
  const int iq = tid >> 2, kq = (tid & 3)*8;

  float* wsW = ws;
  float* wsU = ws + OFF_U;
  float* wsM = ws + OFF_M;
  float* wsCc= ws + OFF_C;

  const float negA = -__expf(A_log[h]);

  { // gate g into sG
    const float* gr = graw + (((size_t)b*Tt + t0 + iq)*Hh + h)*32 + kq;
    const float* db = dt_bias + h*32 + kq;
    #pragma unroll
    for (int r = 0; r < 8; ++r)
      sG[iq*33 + kq + r] = negA * softplusf(gr[r] + db[r]);
  }
  __syncthreads();
  if (tid < 32) { // cumsum over time per k, register-chunked (pipelined loads)
    float c0 = 0.f;
    for (int blk = 0; blk < 4; ++blk) {
      float v[16];
      #pragma unroll
      for (int i = 0; i < 16; ++i) v[i] = sG[(blk*16+i)*33 + tid];
      #pragma unroll
      for (int i = 0; i < 16; ++i) { c0 += v[i]; sG[(blk*16+i)*33 + tid] = c0; }
    }
  }
  { // k row-l2-normalize into sK
    const float* kp = kin + (((size_t)b*Tt + t0 + iq)*Hh + h)*32 + kq;
    float kr[8]; float ss = 0.f;
    #pragma unroll
    for (int r = 0; r < 8; ++r) { kr[r] = kp[r]; ss += kr[r]*kr[r]; }
    ss += __shfl_xor(ss, 1); ss += __shfl_xor(ss, 2);
    const float sc = 1.f / fmaxf(sqrtf(ss), 1e-6f);
    #pragma unroll
    for (int r = 0; r < 8; ++r) sK[iq*33 + kq + r] = kr[r]*sc;
  }
  __syncthreads();

  // ---- Akk in 8-column tiles; P at stride 36 -> vectorized ds_read_b128 ----
  const float b_cm = beta[((size_t)b*Tt + t0 + (tid & 63))*Hh + h];
  float* P  = sT;          // 64x36 (2304 floats)
  float* Qb = sT + 2304;   // 8x32 s32
  const int i64 = tid & 63, jj2 = (tid >> 6)*2;
  for (int jt = 0; jt < 8; ++jt) {
    const int j0 = jt*8;
    {
      float pv[8];
      #pragma unroll
      for (int r = 0; r < 8; ++r) {
        const int idx = iq*33 + kq + r;
        pv[r] = sK[idx] * __expf(fminf(sG[idx] - sG[j0*33 + kq + r], 0.f));
      }
      *(float4*)(P + iq*36 + kq)     = make_float4(pv[0],pv[1],pv[2],pv[3]);
      *(float4*)(P + iq*36 + kq + 4) = make_float4(pv[4],pv[5],pv[6],pv[7]);
    }
    {
      const int jj = tid >> 5, kk = tid & 31;
      Qb[jj*32 + kk] = sK[(j0+jj)*33 + kk] * __expf(sG[j0*33 + kk] - sG[(j0+jj)*33 + kk]);
    }
    __syncthreads();
    float a0 = 0.f, a1 = 0.f;
    #pragma unroll
    for (int hf = 0; hf < 2; ++hf) {
      const int k0 = hf*16;
      #pragma unroll
      for (int t4 = 0; t4 < 4; ++t4) {
        const float4 pa = *(const float4*)(P  + i64*36 + k0 + t4*4);
        const float4 xa = *(const float4*)(Qb + (jj2  )*32 + k0 + t4*4);
        const float4 xb = *(const float4*)(Qb + (jj2+1)*32 + k0 + t4*4);
        a0 += pa.x*xa.x + pa.y*xa.y + pa.z*xa.z + pa.w*xa.w;
        a1 += pa.x*xb.x + pa.y*xb.y + pa.z*xb.z + pa.w*xb.w;
      }
    }
    const int j_0 = j0 + jj2;
    sL[(j_0  )*64 + i64] = (i64 > j_0  ) ? a0*b_cm : 0.f;
    sL[(j_0+1)*64 + i64] = (i64 > j_0+1) ? a1*b_cm : 0.f;
    __syncthreads();
  }

  // ---- Tm = (I + L)^-1, blocked 16x16 forward substitution ----
  for (int e = tid; e < 4096; e += 256) {
    const int row = e >> 6, col = e & 63;
    sT[row*65 + col] = (row == col) ? 1.f : 0.f;
  }
  __syncthreads();
  // diagonal blocks: all cross-iteration deps are lane-local -> no barriers
  if (tid < 64) {
    const int p = tid >> 4, col = tid & 15;
    for (int i = 1; i < 16; ++i) {
      const int gi = p*16 + i, gc = p*16 + col;
      float acc = 0.f;
      for (int j = 0; j < i; ++j)
        acc -= sL[(p*16+j)*64 + gi] * sT[(p*16+j)*65 + gc];
      sT[gi*65 + gc] = acc + ((i == col) ? 1.f : 0.f);
    }
  }
  __syncthreads();
  // off-diagonal blocks: one 16x16 block per wave, 3 barrier levels
  {
    const int wid = tid >> 6;
    const int lane = tid & 63;
    const int ri = lane & 15, c4 = (lane >> 4)*4;
    auto offblk = [&](int p, int q) {
      float a0=0.f, a1=0.f, a2=0.f, a3=0.f;
      for (int m = q; m < p; ++m) {
        #pragma unroll
        for (int j = 0; j < 16; ++j) {
          const float lv = sL[(m*16+j)*64 + p*16+ri];
          const float* tp = sT + (m*16+j)*65 + q*16 + c4;
          a0 += lv*tp[0]; a1 += lv*tp[1]; a2 += lv*tp[2]; a3 += lv*tp[3];
        }
      }
      float* cp = sC2 + wid*272 + ri*17 + c4;
      cp[0]=a0; cp[1]=a1; cp[2]=a2; cp[3]=a3;
      float b0=0.f, b1=0.f, b2=0.f, b3=0.f;
      #pragma unroll
      for (int j = 0; j < 16; ++j) {
        const float tv = sT[(p*16+ri)*65 + p*16 + j];
        const float* cj = sC2 + wid*272 + j*17 + c4;
        b0 += tv*cj[0]; b1 += tv*cj[1]; b2 += tv*cj[2]; b3 += tv*cj[3];
      }
      float* op = sT + (p*16+ri)*65 + q*16 + c4;
      op[0]=-b0; op[1]=-b1; op[2]=-b2; op[3]=-b3;
    };
    if (wid == 0) offblk(1,0); else if (wid == 1) offblk(2,1); else if (wid == 2) offblk(3,2);
    __syncthreads();
    if (wid == 0) offblk(2,0); else if (wid == 1) offblk(3,1);
    __syncthreads();
    if (wid == 0) offblk(3,0);
  }
  __syncthreads();

  { // k_egb (s32 into sL[0..2047]); kd overwrites sK (s33); egl
    const float b_row = beta[((size_t)b*Tt + t0 + iq)*Hh + h];
    #pragma unroll
    for (int r = 0; r < 8; ++r) {
      const int idx = iq*33 + kq + r;
      const float g = sG[idx], kn = sK[idx];
      sL[iq*32 + kq + r] = b_row * kn * __expf(g);
      sK[idx] = kn * __expf(sG[63*33 + kq + r] - g);
    }
    if (tid < 32) sEgl[tid] = __expf(sG[63*33 + tid]);
  }
  __syncthreads();

  { // w = Tm @ k_egb -> global + sG (s32; gcum dead)
    float acc[8] = {0,0,0,0,0,0,0,0};
    for (int j = 0; j <= iq; ++j) {
      const float t = sT[iq*65 + j];
      const float4 e0 = *(const float4*)(sL + j*32 + kq);
      const float4 e1 = *(const float4*)(sL + j*32 + kq + 4);
      acc[0]+=t*e0.x; acc[1]+=t*e0.y; acc[2]+=t*e0.z; acc[3]+=t*e0.w;
      acc[4]+=t*e1.x; acc[5]+=t*e1.y; acc[6]+=t*e1.z; acc[7]+=t*e1.w;
    }
    #pragma unroll
    for (int r = 0; r < 8; ++r) {
      wsW[(size_t)ch*2048 + tid*8 + r] = acc[r];
      sG[iq*32 + kq + r] = acc[r];
    }
  }
  __syncthreads();

  { // vb = beta_j * v into sL (s64)
    #pragma unroll
    for (int r = 0; r < 4; ++r) {
      const int f = tid + 256*r;
      const int j = f >> 4, qd = f & 15;
      const float bj = beta[((size_t)b*Tt + t0 + j)*Hh + h];
      float4 v4 = *(const float4*)(vin + (((size_t)b*Tt + t0 + j)*Hh + h)*64 + qd*4);
      v4.x *= bj; v4.y *= bj; v4.z *= bj; v4.w *= bj;
      *(float4*)(sL + j*64 + qd*4) = v4;
    }
  }
  __syncthreads();

  float uacc[16];
  { // u = Tm @ vb -> wsU (and regs)
    const int vs = (tid & 3)*16;
    #pragma unroll
    for (int r = 0; r < 16; ++r) uacc[r] = 0.f;
    for (int j = 0; j <= iq; ++j) {
      const float t = sT[iq*65 + j];
      const float4 e0 = *(const float4*)(sL + j*64 + vs);
      const float4 e1 = *(const float4*)(sL + j*64 + vs + 4);
      const float4 e2 = *(const float4*)(sL + j*64 + vs + 8);
      const float4 e3 = *(const float4*)(sL + j*64 + vs + 12);
      uacc[0]+=t*e0.x;  uacc[1]+=t*e0.y;  uacc[2]+=t*e0.z;  uacc[3]+=t*e0.w;
      uacc[4]+=t*e1.x;  uacc[5]+=t*e1.y;  uacc[6]+=t*e1.z;  uacc[7]+=t*e1.w;
      uacc[8]+=t*e2.x;  uacc[9]+=t*e2.y;  uacc[10]+=t*e2.z; uacc[11]+=t*e2.w;
      uacc[12]+=t*e3.x; uacc[13]+=t*e3.y; uacc[14]+=t*e3.z; uacc[15]+=t*e3.w;
    }
    #pragma unroll
    for (int rr = 0; rr < 4; ++rr) {
      float4 o4; o4.x=uacc[rr*4]; o4.y=uacc[rr*4+1]; o4.z=uacc[rr*4+2]; o4.w=uacc[rr*4+3];
      *(float4*)(wsU + (size_t)ch*4096 + tid*16 + rr*4) = o4;
    }
  }
  __syncthreads();       // all vb reads done
  { // u into sL (s64)
    const int vs = (tid & 3)*16;
    #pragma unroll
    for (int rr = 0; rr < 4; ++rr) {
      float4 o4; o4.x=uacc[rr*4]; o4.y=uacc[rr*4+1]; o4.z=uacc[rr*4+2]; o4.w=uacc[rr*4+3];
      *(float4*)(sL + iq*64 + vs + rr*4) = o4;
    }
  }
  __syncthreads();

  { // M = diag(egl) - Kd^T W ; C = Kd^T U
    const int a = tid >> 3, b4 = (tid & 7)*4, v8 = (tid & 7)*8;
    float mA[4] = {0,0,0,0};
    float cA[8] = {0,0,0,0,0,0,0,0};
    for (int t = 0; t < 64; ++t) {
      const float kd = sK[t*33 + a];
      const float4 wv = *(const float4*)(sG + t*32 + b4);
      mA[0]+=kd*wv.x; mA[1]+=kd*wv.y; mA[2]+=kd*wv.z; mA[3]+=kd*wv.w;
      const float4 u0 = *(const float4*)(sL + t*64 + v8);
      const float4 u1 = *(const float4*)(sL + t*64 + v8 + 4);
      cA[0]+=kd*u0.x; cA[1]+=kd*u0.y; cA[2]+=kd*u0.z; cA[3]+=kd*u0.w;
      cA[4]+=kd*u1.x; cA[5]+=kd*u1.y; cA[6]+=kd*u1.z; cA[7]+=kd*u1.w;
    }
    float4 m4;
    m4.x = ((a == b4+0) ? sEgl[a] : 0.f) - mA[0];
    m4.y = ((a == b4+1) ? sEgl[a] : 0.f) - mA[1];
    m4.z = ((a == b4+2) ? sEgl[a] : 0.f) - mA[2];
    m4.w = ((a == b4+3) ? sEgl[a] : 0.f) - mA[3];
    *(float4*)(wsM + (size_t)ch*1024 + tid*4) = m4;
    float4 c0, c1;
    c0.x=cA[0]; c0.y=cA[1]; c0.z=cA[2]; c0.w=cA[3];
    c1.x=cA[4]; c1.y=cA[5]; c1.z=cA[6]; c1.w=cA[7];
    *(float4*)(wsCc + (size_t)ch*2048 + tid*8) = c0;
    *(float4*)(wsCc + (size_t)ch*2048 + tid*8 + 4) = c1;
  }
}

// ---------------- scanA: compose 16 chunk maps per segment (V-split x4) ----------------
// 1-deep HBM prefetch; 2 barriers/iteration.
__global__ __launch_bounds__(256) void kda_scanA(float* __restrict__ ws)
{
  __shared__ float sMa[32*33];
  __shared__ float sMc[32*33];
  __shared__ float sCa[32*18];
  const int tid = threadIdx.x;
  const int vt = blockIdx.x & 3, seg = (blockIdx.x >> 2) & 7, bh = blockIdx.x >> 5;
  const int v0 = vt*16;
  const int a = tid >> 3, b4 = (tid & 7)*4, c2 = (tid & 7)*2;
  const float* wsM = ws + OFF_M;
  const float* wsC = ws + OFF_C;

  #pragma unroll
  for (int r = 0; r < 4; ++r) sMa[a*33 + b4 + r] = (a == b4 + r) ? 1.f : 0.f;
  sCa[a*18 + c2] = 0.f; sCa[a*18 + c2 + 1] = 0.f;

  int ch = (seg*16)*32 + bh;
  float4 m4 = *(const float4*)(wsM + (size_t)ch*1024 + tid*4);
  float2 cc = *(const float2*)(wsC + (size_t)ch*2048 + a*64 + v0 + c2);

  for (int i = 0; i < 16; ++i) {
    sMc[a*33+b4+0]=m4.x; sMc[a*33+b4+1]=m4.y; sMc[a*33+b4+2]=m4.z; sMc[a*33+b4+3]=m4.w;
    __syncthreads();
    float4 m4n = m4; float2 ccn = cc;
    if (i < 15) {   // prefetch next chunk while computing this one
      const int chn = (seg*16 + i + 1)*32 + bh;
      m4n = *(const float4*)(wsM + (size_t)chn*1024 + tid*4);
      ccn = *(const float2*)(wsC + (size_t)chn*2048 + a*64 + v0 + c2);
    }
    float cn0 = cc.x, cn1 = cc.y;
    float mn0=0.f, mn1=0.f, mn2=0.f, mn3=0.f;
    for (int bb = 0; bb < 32; ++bb) {
      const float m = sMc[a*33 + bb];
      const float2 s2 = *(const float2*)(sCa + bb*18 + c2);
      cn0 += m*s2.x; cn1 += m*s2.y;
      mn0 += m*sMa[bb*33+b4+0]; mn1 += m*sMa[bb*33+b4+1];
      mn2 += m*sMa[bb*33+b4+2]; mn3 += m*sMa[bb*33+b4+3];
    }
    __syncthreads();
    sCa[a*18+c2] = cn0; sCa[a*18+c2+1] = cn1;
    sMa[a*33+b4+0]=mn0; sMa[a*33+b4+1]=mn1; sMa[a*33+b4+2]=mn2; sMa[a*33+b4+3]=mn3;
    m4 = m4n; cc = ccn;
  }
  // epilogue reads only own-written elements: no barrier needed
  const size_t sid = (size_t)(bh*8 + seg);
  float* wsMs = ws + OFF_MS;
  float* wsCs = ws + OFF_CS;
  if (vt == 0) {
    #pragma unroll
    for (int r = 0; r < 4; ++r) wsMs[sid*1024 + tid*4 + r] = sMa[a*33+b4+r];
  }
  float2 co; co.x = sCa[a*18+c2]; co.y = sCa[a*18+c2+1];
  *(float2*)(wsCs + sid*2048 + a*64 + v0 + c2) = co;
}

// ---------------- scanB: scan 8 segments per bh (V-split x4, grid 128) ----------------
__global__ __launch_bounds__(256) void kda_scanB(float* __restrict__ ws)
{
  __shared__ float sS[32*18];
  __shared__ float sM[32*33];
  const int tid = threadIdx.x;
  const int vt = blockIdx.x & 3, bh = blockIdx.x >> 2;
  const int v0 = vt*16;
  const int a = tid >> 3, b4 = (tid & 7)*4, c2 = (tid & 7)*2;
  const float* wsMs = ws + OFF_MS;
  const float* wsCs = ws + OFF_CS;
  float* wsSs = ws + OFF_SS;

  float s0 = 0.f, s1 = 0.f;
  sS[a*18 + c2] = 0.f; sS[a*18 + c2 + 1] = 0.f;
  const size_t sid0 = (size_t)(bh*8);
  float4 m4 = *(const float4*)(wsMs + sid0*1024 + tid*4);
  float2 cc = *(const float2*)(wsCs + sid0*2048 + a*64 + v0 + c2);

  for (int seg = 0; seg < 8; ++seg) {
    const size_t sid = (size_t)(bh*8 + seg);
    *(float2*)(wsSs + sid*2048 + a*64 + v0 + c2) = make_float2(s0, s1);
    sM[a*33+b4+0]=m4.x; sM[a*33+b4+1]=m4.y; sM[a*33+b4+2]=m4.z; sM[a*33+b4+3]=m4.w;
    __syncthreads();
    float4 m4n = m4; float2 ccn = cc;
    if (seg < 7) {
      m4n = *(const float4*)(wsMs + (sid+1)*1024 + tid*4);
      ccn = *(const float2*)(wsCs + (sid+1)*2048 + a*64 + v0 + c2);
    }
    float n0 = cc.x, n1 = cc.y;
    for (int bb = 0; bb < 32; ++bb) {
      const float m = sM[a*33 + bb];
      const float2 s2 = *(const float2*)(sS + bb*18 + c2);
      n0 += m*s2.x; n1 += m*s2.y;
    }
    __syncthreads();
    s0 = n0; s1 = n1;
    sS[a*18+c2] = s0; sS[a*18+c2+1] = s1;
    m4 = m4n; cc = ccn;
  }
}

// ---------------- scanC: replay chunks, write entering-S over C slot (V-split x4) ----------------
__global__ __launch_bounds__(256) void kda_scanC(float* __restrict__ ws)
{
  __shared__ float sM[32*33];
  __shared__ float sS[32*18];
  const int tid = threadIdx.x;
  const int vt = blockIdx.x & 3, seg = (blockIdx.x >> 2) & 7, bh = blockIdx.x >> 5;
  const int v0 = vt*16;
  const int a = tid >> 3, b4 = (tid & 7)*4, c2 = (tid & 7)*2;
  const float* wsM = ws + OFF_M;
  float* wsC = ws + OFF_C;
  const float* wsSs = ws + OFF_SS;

  const size_t sid = (size_t)(bh*8 + seg);
  float s0, s1;
  {
    float2 sv = *(const float2*)(wsSs + sid*2048 + a*64 + v0 + c2);
    s0 = sv.x; s1 = sv.y;
    sS[a*18 + c2] = s0; sS[a*18 + c2 + 1] = s1;
  }
  int ch = (seg*16)*32 + bh;
  float4 m4 = *(const float4*)(wsM + (size_t)ch*1024 + tid*4);
  float2 cc = *(const float2*)(wsC + (size_t)ch*2048 + a*64 + v0 + c2);

  for (int i = 0; i < 16; ++i) {
    const int chc = (seg*16 + i)*32 + bh;
    sM[a*33+b4+0]=m4.x; sM[a*33+b4+1]=m4.y; sM[a*33+b4+2]=m4.z; sM[a*33+b4+3]=m4.w;
    // entering-S over the consumed C slice (own elements; cc already in regs)
    *(float2*)(wsC + (size_t)chc*2048 + a*64 + v0 + c2) = make_float2(s0, s1);
    __syncthreads();
    float4 m4n = m4; float2 ccn = cc;
    if (i < 15) {   // prefetch next chunk's (M,C); same-thread same-address order vs next overwrite
      const int chn = (seg*16 + i + 1)*32 + bh;
      m4n = *(const float4*)(wsM + (size_t)chn*1024 + tid*4);
      ccn = *(const float2*)(wsC + (size_t)chn*2048 + a*64 + v0 + c2);
    }
    float n0 = cc.x, n1 = cc.y;
    for (int bb = 0; bb < 32; ++bb) {
      const float m = sM[a*33 + bb];
      const float2 s2 = *(const float2*)(sS + bb*18 + c2);
      n0 += m*s2.x; n1 += m*s2.y;
    }
    __syncthreads();
    s0 = n0; s1 = n1;
    sS[a*18+c2] = s0; sS[a*18+c2+1] = s1;
    m4 = m4n; cc = ccn;
  }
}

// ---------------- Phase 3: Aqk + output (o = Aqk@u + (qg - Aqk@w)@S) ----------------
// 256 threads (R0-proven). P stride 36 + chunked cumsum as in phase1.
__global__ __launch_bounds__(256) void kda_phase3(
    const float* __restrict__ qin, const float* __restrict__ kin,
    const float* __restrict__ graw,
    const float* __restrict__ A_log, const float* __restrict__ dt_bias,
    const float* __restrict__ ws, float* __restrict__ out)
{
  __shared__ float sG[64*33];   // gcum (s33) -> S (s64, first 2048)
  __shared__ float sQ[64*33];   // qn -> qeff
  __shared__ float sA[64*65];   // Aqk
  __shared__ float sV[64*64];   // P(s36)/Qb scratch -> w (s32) -> u (s64)

  const int tid = threadIdx.x;
  const int ch = blockIdx.x;
  const int c = ch >> 5, bh = ch & 31;
  const int b = bh >> 4, h = bh & 15;
  const int t0 = c*64;
  const int iq = tid >> 2, kq = (tid & 3)*8;

  const float* wsW = ws;            // w (64x32)
  const float* wsU = ws + OFF_U;    // u (64x64)
  const float* wsS = ws + OFF_C;    // entering S (32x64) written by scanC

  const float negA = -__expf(A_log[h]);
  {
    const float* gr = graw + (((size_t)b*Tt + t0 + iq)*Hh + h)*32 + kq;
    const float* db = dt_bias + h*32 + kq;
    #pragma unroll
    for (int r = 0; r < 8; ++r)
      sG[iq*33 + kq + r] = negA * softplusf(gr[r] + db[r]);
  }
  __syncthreads();
  if (tid < 32) { // register-chunked cumsum
    float c0 = 0.f;
    for (int blk = 0; blk < 4; ++blk) {
      float v[16];
      #pragma unroll
      for (int i = 0; i < 16; ++i) v[i] = sG[(blk*16+i)*33 + tid];
      #pragma unroll
      for (int i = 0; i < 16; ++i) { c0 += v[i]; sG[(blk*16+i)*33 + tid] = c0; }
    }
  }
  float knr[8];
  { // q (l2norm * K^-1/2) into sQ; k (l2norm) in registers
    const float* qp = qin + (((size_t)b*Tt + t0 + iq)*Hh + h)*32 + kq;
    float qr[8]; float ssq = 0.f;
    #pragma unroll
    for (int r = 0; r < 8; ++r) { qr[r] = qp[r]; ssq += qr[r]*qr[r]; }
    ssq += __shfl_xor(ssq, 1); ssq += __shfl_xor(ssq, 2);
    const float scq = 0.17677669529663687f / fmaxf(sqrtf(ssq), 1e-6f);
    #pragma unroll
    for (int r = 0; r < 8; ++r) sQ[iq*33 + kq + r] = qr[r]*scq;

    const float* kp = kin + (((size_t)b*Tt + t0 + iq)*Hh + h)*32 + kq;
    float ssk = 0.f;
    #pragma unroll
    for (int r = 0; r < 8; ++r) { knr[r] = kp[r]; ssk += knr[r]*knr[r]; }
    ssk += __shfl_xor(ssk, 1); ssk += __shfl_xor(ssk, 2);
    const float sck = 1.f / fmaxf(sqrtf(ssk), 1e-6f);
    #pragma unroll
    for (int r = 0; r < 8; ++r) knr[r] *= sck;
  }
  __syncthreads();

  float* P  = sV;          // 64x36
  float* Qb = sV + 2304;   // 8x32 s32
  const int i64 = tid & 63, jj2 = (tid >> 6)*2;
  for (int jt = 0; jt < 8; ++jt) {
    const int j0 = jt*8;
    {
      float pv[8];
      #pragma unroll
      for (int r = 0; r < 8; ++r) {
        const int idx = iq*33 + kq + r;
        pv[r] = sQ[idx] * __expf(fminf(sG[idx] - sG[j0*33 + kq + r], 0.f));
      }
      *(float4*)(P + iq*36 + kq)     = make_float4(pv[0],pv[1],pv[2],pv[3]);
      *(float4*)(P + iq*36 + kq + 4) = make_float4(pv[4],pv[5],pv[6],pv[7]);
    }
    if (iq >= j0 && iq < j0 + 8) {
      const int jj = iq - j0;
      #pragma unroll
      for (int r = 0; r < 8; ++r)
        Qb[jj*32 + kq + r] = knr[r] * __expf(sG[j0*33 + kq + r] - sG[iq*33 + kq + r]);
    }
    __syncthreads();
    float a0 = 0.f, a1 = 0.f;
    #pragma unroll
    for (int hf = 0; hf < 2; ++hf) {
      const int k0 = hf*16;
      #pragma unroll
      for (int t4 = 0; t4 < 4; ++t4) {
        const float4 pa = *(const float4*)(P  + i64*36 + k0 + t4*4);
        const float4 xa = *(const float4*)(Qb + (jj2  )*32 + k0 + t4*4);
        const float4 xb = *(const float4*)(Qb + (jj2+1)*32 + k0 + t4*4);
        a0 += pa.x*xa.x + pa.y*xa.y + pa.z*xa.z + pa.w*xa.w;
        a1 += pa.x*xb.x + pa.y*xb.y + pa.z*xb.z + pa.w*xb.w;
      }
    }
    const int j_0 = j0 + jj2;
    sA[i64*65 + j_0  ] = (i64 >= j_0  ) ? a0 : 0.f;   // incl. diagonal
    sA[i64*65 + j_0+1] = (i64 >= j_0+1) ? a1 : 0.f;
    __syncthreads();
  }

  float qgr[8];
  { // qg = qn * exp(gcum) in registers (own row slice)
    #pragma unroll
    for (int r = 0; r < 8; ++r) {
      const int idx = iq*33 + kq + r;
      qgr[r] = sQ[idx] * __expf(sG[idx]);
    }
  }
  __syncthreads();   // gcum + sV scratch dead
  { // stage S into sG (s64 flat) and w into sV (s32 flat)
    #pragma unroll
    for (int rr = 0; rr < 2; ++rr) {
      const int f = tid + 256*rr;
      *(float4*)(sG + f*4) = *(const float4*)(wsS + (size_t)ch*2048 + f*4);
    }
    *(float4*)(sV + tid*8)     = *(const float4*)(wsW + (size_t)ch*2048 + tid*8);
    *(float4*)(sV + tid*8 + 4) = *(const float4*)(wsW + (size_t)ch*2048 + tid*8 + 4);
  }
  __syncthreads();
  { // qeff = qg - Aqk @ w  -> sQ
    float qe[8];
    #pragma unroll
    for (int r = 0; r < 8; ++r) qe[r] = qgr[r];
    for (int j = 0; j <= iq; ++j) {
      const float av = sA[iq*65 + j];
      const float4 w0 = *(const float4*)(sV + j*32 + kq);
      const float4 w1 = *(const float4*)(sV + j*32 + kq + 4);
      qe[0]-=av*w0.x; qe[1]-=av*w0.y; qe[2]-=av*w0.z; qe[3]-=av*w0.w;
      qe[4]-=av*w1.x; qe[5]-=av*w1.y; qe[6]-=av*w1.z; qe[7]-=av*w1.w;
    }
    #pragma unroll
    for (int r = 0; r < 8; ++r) sQ[iq*33 + kq + r] = qe[r];
  }
  __syncthreads();   // qeff visible; sV-w reads done
  { // stage u into sV (s64)
    #pragma unroll
    for (int rr = 0; rr < 4; ++rr) {
      const int f = tid + 256*rr;
      *(float4*)(sV + f*4) = *(const float4*)(wsU + (size_t)ch*4096 + f*4);
    }
  }
  __syncthreads();
  { // o = qeff @ S + Aqk @ u
    const int vs = (tid & 3)*16;
    float acc[16];
    #pragma unroll
    for (int r = 0; r < 16; ++r) acc[r] = 0.f;
    for (int kk = 0; kk < 32; ++kk) {
      const float qv = sQ[iq*33 + kk];
      const float4 s0 = *(const float4*)(sG + kk*64 + vs);
      const float4 s1 = *(const float4*)(sG + kk*64 + vs + 4);
      const float4 s2 = *(const float4*)(sG + kk*64 + vs + 8);
      const float4 s3 = *(const float4*)(sG + kk*64 + vs + 12);
      acc[0]+=qv*s0.x;  acc[1]+=qv*s0.y;  acc[2]+=qv*s0.z;  acc[3]+=qv*s0.w;
      acc[4]+=qv*s1.x;  acc[5]+=qv*s1.y;  acc[6]+=qv*s1.z;  acc[7]+=qv*s1.w;
      acc[8]+=qv*s2.x;  acc[9]+=qv*s2.y;  acc[10]+=qv*s2.z; acc[11]+=qv*s2.w;
      acc[12]+=qv*s3.x; acc[13]+=qv*s3.y; acc[14]+=qv*s3.z; acc[15]+=qv*s3.w;
    }
    for (int j = 0; j <= iq; ++j) {
      const float av = sA[iq*65 + j];
      const float4 u0 = *(const float4*)(sV + j*64 + vs);
      const float4 u1 = *(const float4*)(sV + j*64 + vs + 4);
      const float4 u2 = *(const float4*)(sV + j*64 + vs + 8);
      const float4 u3 = *(const float4*)(sV + j*64 + vs + 12);
      acc[0]+=av*u0.x;  acc[1]+=av*u0.y;  acc[2]+=av*u0.z;  acc[3]+=av*u0.w;
      acc[4]+=av*u1.x;  acc[5]+=av*u1.y;  acc[6]+=av*u1.z;  acc[7]+=av*u1.w;
      acc[8]+=av*u2.x;  acc[9]+=av*u2.y;  acc[10]+=av*u2.z; acc[11]+=av*u2.w;
      acc[12]+=av*u3.x; acc[13]+=av*u3.y; acc[14]+=av*u3.z; acc[15]+=av*u3.w;
    }
    float* op = out + (((size_t)b*Tt + t0 + iq)*Hh + h)*64 + vs;
    #pragma unroll
    for (int rr = 0; rr < 4; ++rr) {
      float4 o4; o4.x=acc[rr*4]; o4.y=acc[rr*4+1]; o4.z=acc[rr*4+2]; o4.w=acc[rr*4+3];
      *(float4*)(op + rr*4) = o4;
    }
  }
}

extern "C" void kernel_launch(void* const* d_in, const int* in_sizes, int n_in,
                              void* d_out, int out_size, void* d_ws, size_t ws_size,
                              hipStream_t stream) {
  const float* q    = (const float*)d_in[0];
  const float* k    = (const float*)d_in[1];
  const float* v    = (const float*)d_in[2];
  const float* graw = (const float*)d_in[3];
  const float* beta = (const float*)d_in[4];
  const float* A_log= (const float*)d_in[5];
  const float* dtb  = (const float*)d_in[6];
  float* out = (float*)d_out;
  float* ws  = (float*)d_ws;
  // requires ws_size >= 156.3 MB

  kda_phase1<<<NCH, 256, 0, stream>>>(k, v, graw, beta, A_log, dtb, ws);
  kda_scanA<<<1024, 256, 0, stream>>>(ws);
  kda_scanB<<<128, 256, 0, stream>>>(ws);
  kda_scanC<<<1024, 256, 0, stream>>>(ws);
  kda_phase3<<<NCH, 256, 0, stream>>>(q, k, graw, A_log, dtb, ws, out);
}